// Round 1
// 813.868 us; speedup vs baseline: 1.0904x; 1.0904x over previous
//
#include <hip/hip_runtime.h>
#include <hip/hip_bf16.h>
#include <math.h>

#define SS 2048
#define DD 1024
#define NH 16
#define NKVH 4
#define HDIM 64
#define NE 8
#define NI 3584
#define QKVN 1536
#define PCAP 5120
#define NTILEMAX 40   // PCAP/128

typedef unsigned short u16;
typedef short short8 __attribute__((ext_vector_type(8)));
typedef float floatx4 __attribute__((ext_vector_type(4)));

__device__ inline u16 f2bf(float f) {
  unsigned u = __float_as_uint(f);
  unsigned r = u + 0x7fffu + ((u >> 16) & 1u);
  return (u16)(r >> 16);
}
__device__ inline float bf2f(u16 h) { return __uint_as_float((unsigned)h << 16); }

// ---------------- fp32 -> bf16 bulk convert ----------------
__global__ void f32_to_bf16_kernel(const float* __restrict__ in, u16* __restrict__ out, int n4) {
  int i = blockIdx.x * 256 + threadIdx.x;
  if (i >= n4) return;
  float4 v = ((const float4*)in)[i];
  ((ushort4*)out)[i] = make_ushort4(f2bf(v.x), f2bf(v.y), f2bf(v.z), f2bf(v.w));
}

// ---------------- RMSNorm ----------------
__global__ void rmsnorm_kernel(const float* __restrict__ x, const float* __restrict__ w,
                               float* __restrict__ o32, u16* __restrict__ o16) {
  int row = blockIdx.x;
  int t = threadIdx.x;
  float4 v = ((const float4*)(x + (size_t)row * DD))[t];
  float ss = v.x * v.x + v.y * v.y + v.z * v.z + v.w * v.w;
  for (int o = 32; o > 0; o >>= 1) ss += __shfl_xor(ss, o);
  __shared__ float red[4];
  if ((t & 63) == 0) red[t >> 6] = ss;
  __syncthreads();
  float tot = red[0] + red[1] + red[2] + red[3];
  float r = rsqrtf(tot * (1.f / DD) + 1e-5f);
  float4 wv = ((const float4*)w)[t];
  float4 o;
  o.x = v.x * r * wv.x; o.y = v.y * r * wv.y; o.z = v.z * r * wv.z; o.w = v.w * r * wv.w;
  if (o32) ((float4*)(o32 + (size_t)row * DD))[t] = o;
  if (o16) ((ushort4*)(o16 + (size_t)row * DD))[t] =
      make_ushort4(f2bf(o.x), f2bf(o.y), f2bf(o.z), f2bf(o.w));
}

// ---------------- Plain MFMA GEMM (qkv, wo): C = A @ B^T (+addend) ----------------
__global__ __launch_bounds__(256) void gemm128(
    const u16* __restrict__ A, const u16* __restrict__ B,
    float* __restrict__ C, const float* __restrict__ addend, int N, int K) {
  __shared__ u16 As[128 * 32];
  __shared__ u16 Bs[128 * 32];
  int tid = threadIdx.x;
  int bm = blockIdx.x * 128;
  int bn = blockIdx.y * 128;
  const u16* Ag = A + (size_t)bm * K;
  const u16* Bg = B + (size_t)bn * K;
  int wave = tid >> 6, lane = tid & 63;
  int wm = wave >> 1, wn = wave & 1;
  int ml = lane & 15, quad = lane >> 4;

  floatx4 acc[4][4];
#pragma unroll
  for (int i = 0; i < 4; i++)
#pragma unroll
    for (int j = 0; j < 4; j++) acc[i][j] = (floatx4){0.f, 0.f, 0.f, 0.f};

  for (int k0 = 0; k0 < K; k0 += 32) {
#pragma unroll
    for (int r = 0; r < 2; r++) {
      int s = tid + r * 256;
      int row = s >> 2, kc = (s & 3) * 8;
      __builtin_amdgcn_global_load_lds(
          (const __attribute__((address_space(1))) unsigned*)(Ag + (size_t)row * K + k0 + kc),
          (__attribute__((address_space(3))) unsigned*)(As + s * 8), 16, 0, 0);
      __builtin_amdgcn_global_load_lds(
          (const __attribute__((address_space(1))) unsigned*)(Bg + (size_t)row * K + k0 + kc),
          (__attribute__((address_space(3))) unsigned*)(Bs + s * 8), 16, 0, 0);
    }
    __syncthreads();
    short8 a[4], b[4];
#pragma unroll
    for (int i = 0; i < 4; i++)
      a[i] = *(const short8*)(As + ((wm * 64 + i * 16 + ml) * 32 + quad * 8));
#pragma unroll
    for (int j = 0; j < 4; j++)
      b[j] = *(const short8*)(Bs + ((wn * 64 + j * 16 + ml) * 32 + quad * 8));
#pragma unroll
    for (int i = 0; i < 4; i++)
#pragma unroll
      for (int j = 0; j < 4; j++)
        acc[i][j] = __builtin_amdgcn_mfma_f32_16x16x32_bf16(a[i], b[j], acc[i][j], 0, 0, 0);
    __syncthreads();
  }
#pragma unroll
  for (int i = 0; i < 4; i++) {
#pragma unroll
    for (int j = 0; j < 4; j++) {
#pragma unroll
      for (int r = 0; r < 4; r++) {
        int row = bm + wm * 64 + i * 16 + quad * 4 + r;
        int col = bn + wn * 64 + j * 16 + ml;
        size_t idx = (size_t)row * N + col;
        float v = acc[i][j][r];
        if (addend) v += addend[idx];
        C[idx] = v;
      }
    }
  }
}

// ---------------- MoE stage 1 fused: x13 = silu(X@w1^T) * (X@w3^T), bf16 out ----------------
// Re-tiled 128(M)x64(N): dual accumulators now fit 64 regs/thread total ->
// ~3 blocks/CU occupancy (was ~1 block/CU at 128x128 with 128 accum regs).
// Per-K-step intensity identical to gemm128 (16KB staged, 16 MFMA/wave).
__global__ __launch_bounds__(256, 3) void moe_stage1(
    const u16* __restrict__ xslot, const u16* __restrict__ w1b, const u16* __restrict__ w3b,
    const int* __restrict__ tmap, u16* __restrict__ x13) {
  __shared__ u16 As[128 * 32];
  __shared__ u16 B1s[64 * 32];
  __shared__ u16 B3s[64 * 32];
  if ((int)blockIdx.x >= tmap[0]) return;
  int entry = tmap[1 + blockIdx.x];
  int e = entry & 7;
  int row0 = (entry >> 3) * 128;
  int bn = blockIdx.y * 64;
  const u16* Ag = xslot + (size_t)row0 * DD;
  const u16* B1g = w1b + (size_t)e * NI * DD + (size_t)bn * DD;
  const u16* B3g = w3b + (size_t)e * NI * DD + (size_t)bn * DD;
  int tid = threadIdx.x, wave = tid >> 6, lane = tid & 63;
  int wm = wave >> 1, wn = wave & 1;
  int ml = lane & 15, quad = lane >> 4;

  floatx4 acc1[4][2], acc3[4][2];
#pragma unroll
  for (int i = 0; i < 4; i++)
#pragma unroll
    for (int j = 0; j < 2; j++) {
      acc1[i][j] = (floatx4){0.f, 0.f, 0.f, 0.f};
      acc3[i][j] = (floatx4){0.f, 0.f, 0.f, 0.f};
    }

  for (int k0 = 0; k0 < DD; k0 += 32) {
#pragma unroll
    for (int r = 0; r < 2; r++) {
      int s = tid + r * 256;
      int row = s >> 2, kc = (s & 3) * 8;
      __builtin_amdgcn_global_load_lds(
          (const __attribute__((address_space(1))) unsigned*)(Ag + (size_t)row * DD + k0 + kc),
          (__attribute__((address_space(3))) unsigned*)(As + s * 8), 16, 0, 0);
    }
    {
      int row = tid >> 2, kc = (tid & 3) * 8;
      __builtin_amdgcn_global_load_lds(
          (const __attribute__((address_space(1))) unsigned*)(B1g + (size_t)row * DD + k0 + kc),
          (__attribute__((address_space(3))) unsigned*)(B1s + tid * 8), 16, 0, 0);
      __builtin_amdgcn_global_load_lds(
          (const __attribute__((address_space(1))) unsigned*)(B3g + (size_t)row * DD + k0 + kc),
          (__attribute__((address_space(3))) unsigned*)(B3s + tid * 8), 16, 0, 0);
    }
    __syncthreads();
    short8 a[4], b1[2], b3[2];
#pragma unroll
    for (int i = 0; i < 4; i++)
      a[i] = *(const short8*)(As + ((wm * 64 + i * 16 + ml) * 32 + quad * 8));
#pragma unroll
    for (int j = 0; j < 2; j++) {
      b1[j] = *(const short8*)(B1s + ((wn * 32 + j * 16 + ml) * 32 + quad * 8));
      b3[j] = *(const short8*)(B3s + ((wn * 32 + j * 16 + ml) * 32 + quad * 8));
    }
#pragma unroll
    for (int i = 0; i < 4; i++)
#pragma unroll
      for (int j = 0; j < 2; j++) {
        acc1[i][j] = __builtin_amdgcn_mfma_f32_16x16x32_bf16(a[i], b1[j], acc1[i][j], 0, 0, 0);
        acc3[i][j] = __builtin_amdgcn_mfma_f32_16x16x32_bf16(a[i], b3[j], acc3[i][j], 0, 0, 0);
      }
    __syncthreads();
  }
#pragma unroll
  for (int i = 0; i < 4; i++) {
#pragma unroll
    for (int j = 0; j < 2; j++) {
#pragma unroll
      for (int r = 0; r < 4; r++) {
        int row = row0 + wm * 64 + i * 16 + quad * 4 + r;
        int col = bn + wn * 32 + j * 16 + ml;
        float v1 = acc1[i][j][r], v3 = acc3[i][j][r];
        float sil = v1 / (1.f + __expf(-v1));
        x13[(size_t)row * NI + col] = f2bf(sil * v3);
      }
    }
  }
}

// ---------------- MoE stage 2 split-K=2: pbuf[kh] = x13 @ w2^T (fp32 partials) ----------------
__global__ __launch_bounds__(256) void moe_stage2(
    const u16* __restrict__ x13, const u16* __restrict__ w2b,
    const int* __restrict__ tmap, float* __restrict__ pbuf) {
  __shared__ u16 As[128 * 32];
  __shared__ u16 Bs[128 * 32];
  if ((int)blockIdx.x >= tmap[0]) return;
  int entry = tmap[1 + blockIdx.x];
  int e = entry & 7;
  int row0 = (entry >> 3) * 128;
  int nt = blockIdx.y & 7, kh = blockIdx.y >> 3;
  int bn = nt * 128;
  int kbeg = kh * (NI / 2), kend = kbeg + NI / 2;
  const u16* Ag = x13 + (size_t)row0 * NI;
  const u16* Bg = w2b + (size_t)e * DD * NI + (size_t)bn * NI;
  float* Cp = pbuf + (size_t)kh * PCAP * DD;
  int tid = threadIdx.x, wave = tid >> 6, lane = tid & 63;
  int wm = wave >> 1, wn = wave & 1;
  int ml = lane & 15, quad = lane >> 4;

  floatx4 acc[4][4];
#pragma unroll
  for (int i = 0; i < 4; i++)
#pragma unroll
    for (int j = 0; j < 4; j++) acc[i][j] = (floatx4){0.f, 0.f, 0.f, 0.f};

  for (int k0 = kbeg; k0 < kend; k0 += 32) {
#pragma unroll
    for (int r = 0; r < 2; r++) {
      int s = tid + r * 256;
      int row = s >> 2, kc = (s & 3) * 8;
      __builtin_amdgcn_global_load_lds(
          (const __attribute__((address_space(1))) unsigned*)(Ag + (size_t)row * NI + k0 + kc),
          (__attribute__((address_space(3))) unsigned*)(As + s * 8), 16, 0, 0);
      __builtin_amdgcn_global_load_lds(
          (const __attribute__((address_space(1))) unsigned*)(Bg + (size_t)row * NI + k0 + kc),
          (__attribute__((address_space(3))) unsigned*)(Bs + s * 8), 16, 0, 0);
    }
    __syncthreads();
    short8 a[4], b[4];
#pragma unroll
    for (int i = 0; i < 4; i++)
      a[i] = *(const short8*)(As + ((wm * 64 + i * 16 + ml) * 32 + quad * 8));
#pragma unroll
    for (int j = 0; j < 4; j++)
      b[j] = *(const short8*)(Bs + ((wn * 64 + j * 16 + ml) * 32 + quad * 8));
#pragma unroll
    for (int i = 0; i < 4; i++)
#pragma unroll
      for (int j = 0; j < 4; j++)
        acc[i][j] = __builtin_amdgcn_mfma_f32_16x16x32_bf16(a[i], b[j], acc[i][j], 0, 0, 0);
    __syncthreads();
  }
#pragma unroll
  for (int i = 0; i < 4; i++) {
#pragma unroll
    for (int j = 0; j < 4; j++) {
#pragma unroll
      for (int r = 0; r < 4; r++) {
        int row = row0 + wm * 64 + i * 16 + quad * 4 + r;
        int col = bn + wn * 64 + j * 16 + ml;
        Cp[(size_t)row * DD + col] = acc[i][j][r];
      }
    }
  }
}

// ---------------- RoPE: fp32 qkv -> bf16 qT [NH][S][64] (scaled 1/8), kT [NKVH][S][64] ----------------
__global__ void rope_kernel(const float* __restrict__ qkv, const float* __restrict__ freqs,
                            u16* __restrict__ qT, u16* __restrict__ kT) {
  int s = blockIdx.x;
  int tid = threadIdx.x;
#pragma unroll
  for (int r = 0; r < 2; r++) {
    int tt = r * 256 + tid;
    int hh = tt >> 5, i = tt & 31;
    const float* p = qkv + (size_t)s * QKVN + hh * 64 + 2 * i;
    float c = freqs[(s * 32 + i) * 2], sn = freqs[(s * 32 + i) * 2 + 1];
    float x0 = p[0], x1 = p[1];
    float r0 = (x0 * c - x1 * sn) * 0.125f;
    float r1 = (x1 * c + x0 * sn) * 0.125f;
    unsigned pk = (unsigned)f2bf(r0) | ((unsigned)f2bf(r1) << 16);
    *(unsigned*)(qT + ((size_t)hh * SS + s) * 64 + 2 * i) = pk;
  }
  if (tid < 128) {
    int hh = tid >> 5, i = tid & 31;
    const float* p = qkv + (size_t)s * QKVN + DD + hh * 64 + 2 * i;
    float c = freqs[(s * 32 + i) * 2], sn = freqs[(s * 32 + i) * 2 + 1];
    float x0 = p[0], x1 = p[1];
    float r0 = x0 * c - x1 * sn;
    float r1 = x1 * c + x0 * sn;
    unsigned pk = (unsigned)f2bf(r0) | ((unsigned)f2bf(r1) << 16);
    *(unsigned*)(kT + ((size_t)hh * SS + s) * 64 + 2 * i) = pk;
  }
}

// ---------------- V transpose: qkv v-part -> vT2 [NKVH*64][S] bf16 ----------------
__global__ void vtrans_kernel(const float* __restrict__ qkv, u16* __restrict__ vT2) {
  __shared__ u16 tile[64][65];
  int bs = blockIdx.x * 64;
  int bc = blockIdx.y * 64;
  int tid = threadIdx.x;
#pragma unroll
  for (int it = 0; it < 4; it++) {
    int idx = it * 256 + tid;
    int r = idx >> 4, c4 = idx & 15;
    float4 v = *(const float4*)(qkv + (size_t)(bs + r) * QKVN + DD + 256 + bc + c4 * 4);
    tile[r][c4 * 4 + 0] = f2bf(v.x);
    tile[r][c4 * 4 + 1] = f2bf(v.y);
    tile[r][c4 * 4 + 2] = f2bf(v.z);
    tile[r][c4 * 4 + 3] = f2bf(v.w);
  }
  __syncthreads();
#pragma unroll
  for (int it = 0; it < 4; it++) {
    int idx = it * 256 + tid;
    int cc = idx >> 4, s4 = idx & 15;
    ushort4 o = make_ushort4(tile[s4 * 4 + 0][cc], tile[s4 * 4 + 1][cc],
                             tile[s4 * 4 + 2][cc], tile[s4 * 4 + 3][cc]);
    *(ushort4*)(vT2 + (size_t)(bc + cc) * SS + bs + s4 * 4) = o;
  }
}

// ---------------- Flash attention: BQ=128 (4 waves x 32 rows), BKV=64, MFMA ----------------
#define BQ 128
#define BKV 64
__global__ __launch_bounds__(256) void attn_flash(const u16* __restrict__ qT,
                                                  const u16* __restrict__ kT,
                                                  const u16* __restrict__ vT2,
                                                  u16* __restrict__ y) {
  __shared__ u16 Ks[2 * 64 * 32];
  __shared__ u16 Vs[2 * 64 * 32];
  __shared__ u16 Ps[2 * 128 * 36];
  int t = blockIdx.x;
  int h = blockIdx.y;
  int kvh = h >> 2;
  int bq = t * BQ;
  int tid = threadIdx.x, wave = tid >> 6, lane = tid & 63;
  int ml = lane & 15, quad = lane >> 4;

  short8 qf[2][2];
#pragma unroll
  for (int i = 0; i < 2; i++)
#pragma unroll
    for (int c = 0; c < 2; c++)
      qf[i][c] = *(const short8*)(qT + ((size_t)h * SS + bq + wave * 32 + i * 16 + ml) * 64 +
                                  c * 32 + quad * 8);

  float m_i[2][4], l_i[2][4];
  floatx4 o_acc[2][4];
#pragma unroll
  for (int i = 0; i < 2; i++)
#pragma unroll
    for (int r = 0; r < 4; r++) {
      m_i[i][r] = -1e30f;
      l_i[i][r] = 0.f;
      o_acc[i][r] = (floatx4){0.f, 0.f, 0.f, 0.f};
    }

  int nkv = 2 * t + 2;
  for (int kt = 0; kt < nkv; kt++) {
    int bk = kt * BKV;
    __syncthreads();
#pragma unroll
    for (int r = 0; r < 2; r++) {
      int ch = r * 256 + tid;
      int c = ch >> 8, srow = (ch >> 2) & 63, o8 = ch & 3;
      __builtin_amdgcn_global_load_lds(
          (const __attribute__((address_space(1))) unsigned*)(
              kT + ((size_t)kvh * SS + bk + srow) * 64 + c * 32 + o8 * 8),
          (__attribute__((address_space(3))) unsigned*)(Ks + ch * 8), 16, 0, 0);
      __builtin_amdgcn_global_load_lds(
          (const __attribute__((address_space(1))) unsigned*)(
              vT2 + ((size_t)kvh * 64 + srow) * SS + bk + c * 32 + o8 * 8),
          (__attribute__((address_space(3))) unsigned*)(Vs + ch * 8), 16, 0, 0);
    }
    __syncthreads();

    floatx4 s_acc[2][4];
#pragma unroll
    for (int i = 0; i < 2; i++)
#pragma unroll
      for (int j = 0; j < 4; j++) s_acc[i][j] = (floatx4){0.f, 0.f, 0.f, 0.f};
#pragma unroll
    for (int c = 0; c < 2; c++) {
#pragma unroll
      for (int jk = 0; jk < 4; jk++) {
        short8 kf = *(const short8*)(Ks + c * 2048 + (jk * 16 + ml) * 32 + quad * 8);
#pragma unroll
        for (int i = 0; i < 2; i++)
          s_acc[i][jk] = __builtin_amdgcn_mfma_f32_16x16x32_bf16(qf[i][c], kf, s_acc[i][jk], 0, 0, 0);
      }
    }
    if (bk + BKV - 1 > bq) {
#pragma unroll
      for (int i = 0; i < 2; i++)
#pragma unroll
        for (int jk = 0; jk < 4; jk++)
#pragma unroll
          for (int r = 0; r < 4; r++) {
            int row = bq + wave * 32 + i * 16 + quad * 4 + r;
            int col = bk + jk * 16 + ml;
            if (col > row) s_acc[i][jk][r] = -1e30f;
          }
    }
#pragma unroll
    for (int i = 0; i < 2; i++) {
#pragma unroll
      for (int r = 0; r < 4; r++) {
        float mx = -1e30f;
#pragma unroll
        for (int jk = 0; jk < 4; jk++) mx = fmaxf(mx, s_acc[i][jk][r]);
        for (int o = 1; o < 16; o <<= 1) mx = fmaxf(mx, __shfl_xor(mx, o));
        float mnew = fmaxf(m_i[i][r], mx);
        float alpha = __expf(m_i[i][r] - mnew);
        m_i[i][r] = mnew;
        float rs = 0.f;
#pragma unroll
        for (int jk = 0; jk < 4; jk++) {
          float p = __expf(s_acc[i][jk][r] - mnew);
          s_acc[i][jk][r] = p;
          rs += p;
        }
        for (int o = 1; o < 16; o <<= 1) rs += __shfl_xor(rs, o);
        l_i[i][r] = l_i[i][r] * alpha + rs;
#pragma unroll
        for (int jd = 0; jd < 4; jd++) o_acc[i][jd][r] *= alpha;
      }
    }
#pragma unroll
    for (int i = 0; i < 2; i++)
#pragma unroll
      for (int jk = 0; jk < 4; jk++)
#pragma unroll
        for (int r = 0; r < 4; r++) {
          int row = wave * 32 + i * 16 + quad * 4 + r;
          int col = jk * 16 + ml;
          Ps[(col >> 5) * (128 * 36) + row * 36 + (col & 31)] = f2bf(s_acc[i][jk][r]);
        }
#pragma unroll
    for (int kc = 0; kc < 2; kc++) {
      short8 pf[2];
#pragma unroll
      for (int i = 0; i < 2; i++)
        pf[i] = *(const short8*)(Ps + kc * (128 * 36) + (wave * 32 + i * 16 + ml) * 36 + quad * 8);
#pragma unroll
      for (int jd = 0; jd < 4; jd++) {
        short8 vf = *(const short8*)(Vs + kc * 2048 + (jd * 16 + ml) * 32 + quad * 8);
#pragma unroll
        for (int i = 0; i < 2; i++)
          o_acc[i][jd] = __builtin_amdgcn_mfma_f32_16x16x32_bf16(pf[i], vf, o_acc[i][jd], 0, 0, 0);
      }
    }
  }
#pragma unroll
  for (int i = 0; i < 2; i++) {
    float inv[4];
#pragma unroll
    for (int r = 0; r < 4; r++) inv[r] = 1.f / l_i[i][r];
#pragma unroll
    for (int jd = 0; jd < 4; jd++)
#pragma unroll
      for (int r = 0; r < 4; r++) {
        int row = bq + wave * 32 + i * 16 + quad * 4 + r;
        int col = h * 64 + jd * 16 + ml;
        y[(size_t)row * DD + col] = f2bf(o_acc[i][jd][r] * inv[r]);
      }
  }
}

// ---------------- Gate ----------------
__global__ __launch_bounds__(64) void gate_kernel(const float* __restrict__ hf,
                                                  const float* __restrict__ gw,
                                                  int* __restrict__ ei, float* __restrict__ ew,
                                                  int* __restrict__ cnt) {
  int t = blockIdx.x;
  int lane = threadIdx.x;
  const float* xr = hf + (size_t)t * DD;
  float acc[NE] = {};
  for (int c = 0; c < DD / 64; c++) {
    float xv = xr[lane + 64 * c];
#pragma unroll
    for (int e = 0; e < NE; e++) acc[e] += xv * gw[e * DD + lane + 64 * c];
  }
#pragma unroll
  for (int e = 0; e < NE; e++)
    for (int o = 32; o > 0; o >>= 1) acc[e] += __shfl_xor(acc[e], o);
  if (lane == 0) {
    float mx = acc[0];
    for (int e = 1; e < NE; e++) mx = fmaxf(mx, acc[e]);
    float p[NE], sum = 0.f;
    for (int e = 0; e < NE; e++) { p[e] = __expf(acc[e] - mx); sum += p[e]; }
    for (int e = 0; e < NE; e++) p[e] /= sum;
    int i0 = 0;
    for (int e = 1; e < NE; e++) if (p[e] > p[i0]) i0 = e;
    int i1 = (i0 == 0) ? 1 : 0;
    for (int e = 0; e < NE; e++) if (e != i0 && p[e] > p[i1]) i1 = e;
    float w0 = p[i0], w1 = p[i1], s = w0 + w1;
    ei[t * 2] = i0; ei[t * 2 + 1] = i1;
    ew[t * 2] = w0 / s; ew[t * 2 + 1] = w1 / s;
    atomicAdd(&cnt[i0], 1);
    atomicAdd(&cnt[i1], 1);
  }
}

__global__ void zero_cnt_kernel(int* cnt) {
  if (threadIdx.x < NE) cnt[threadIdx.x] = 0;
}

__global__ void prefix_kernel(const int* __restrict__ cnt, int* __restrict__ poff,
                              int* __restrict__ fill) {
  if (threadIdx.x == 0) {
    int pacc = 0;
    for (int e = 0; e < NE; e++) {
      poff[e] = pacc;
      pacc += (cnt[e] + 127) & ~127;
    }
    poff[NE] = pacc;
  }
  if (threadIdx.x < NE) fill[threadIdx.x] = 0;
}

// tmap[0] = ntiles, tmap[1+i] = (rowoff128 << 3) | expert
__global__ void tilemap_kernel(const int* __restrict__ poff, int* __restrict__ tmap) {
  if (threadIdx.x == 0) {
    int n = 0;
    for (int e = 0; e < NE; e++) {
      int r0 = poff[e] >> 7, r1 = poff[e + 1] >> 7;
      for (int r = r0; r < r1; r++) tmap[1 + n++] = (r << 3) | e;
    }
    tmap[0] = n;
  }
}

__global__ void fill_kernel(const int* __restrict__ ei, const int* __restrict__ poff,
                            int* __restrict__ fill, int* __restrict__ slot_of) {
  int t = blockIdx.x * blockDim.x + threadIdx.x;
  if (t >= SS) return;
  for (int a = 0; a < 2; a++) {
    int e = ei[t * 2 + a];
    int pos = atomicAdd(&fill[e], 1);
    slot_of[t * 2 + a] = poff[e] + pos;
  }
}

__global__ void gather_kernel(const u16* __restrict__ hf16, const int* __restrict__ slot_of,
                              u16* __restrict__ xslot) {
  int t = blockIdx.x;
  uint2 v = ((const uint2*)(hf16 + (size_t)t * DD))[threadIdx.x];
  for (int a = 0; a < 2; a++) {
    int slot = slot_of[t * 2 + a];
    ((uint2*)(xslot + (size_t)slot * DD))[threadIdx.x] = v;
  }
}

// out = h + w0*(p0[s0]+p1[s0]) + w1*(p0[s1]+p1[s1])
__global__ void final_kernel(const float* __restrict__ h, const float* __restrict__ p0,
                             const float* __restrict__ p1, const int* __restrict__ slot_of,
                             const float* __restrict__ ew, float* __restrict__ out) {
  int t = blockIdx.x;
  int s0 = slot_of[t * 2], s1 = slot_of[t * 2 + 1];
  float w0 = ew[t * 2], w1 = ew[t * 2 + 1];
  float4 hv = ((const float4*)(h + (size_t)t * DD))[threadIdx.x];
  float4 a0 = ((const float4*)(p0 + (size_t)s0 * DD))[threadIdx.x];
  float4 a1 = ((const float4*)(p1 + (size_t)s0 * DD))[threadIdx.x];
  float4 b0 = ((const float4*)(p0 + (size_t)s1 * DD))[threadIdx.x];
  float4 b1 = ((const float4*)(p1 + (size_t)s1 * DD))[threadIdx.x];
  float4 o;
  o.x = hv.x + w0 * (a0.x + a1.x) + w1 * (b0.x + b1.x);
  o.y = hv.y + w0 * (a0.y + a1.y) + w1 * (b0.y + b1.y);
  o.z = hv.z + w0 * (a0.z + a1.z) + w1 * (b0.z + b1.z);
  o.w = hv.w + w0 * (a0.w + a1.w) + w1 * (b0.w + b1.w);
  ((float4*)(out + (size_t)t * DD))[threadIdx.x] = o;
}

extern "C" void kernel_launch(void* const* d_in, const int* in_sizes, int n_in,
                              void* d_out, int out_size, void* d_ws, size_t ws_size,
                              hipStream_t stream) {
  const float* x = (const float*)d_in[0];
  const float* wqkv = (const float*)d_in[1];
  const float* wo = (const float*)d_in[2];
  const float* gate_w = (const float*)d_in[3];
  const float* w1 = (const float*)d_in[4];
  const float* w2 = (const float*)d_in[5];
  const float* w3 = (const float*)d_in[6];
  const float* attn_norm_w = (const float*)d_in[7];
  const float* ffn_norm_w = (const float*)d_in[8];
  const float* freqs = (const float*)d_in[9];
  float* out = (float*)d_out;

  char* ws = (char*)d_ws;
  size_t off = 0;
  auto alloc = [&](size_t bytes) -> char* {
    char* p = ws + off;
    off = (off + bytes + 255) & ~(size_t)255;
    return p;
  };
  u16* hn16    = (u16*)alloc((size_t)SS * DD * 2);   // aliased as qT after qkv GEMM
  float* qkv   = (float*)alloc((size_t)SS * QKVN * 4);
  u16* y16     = (u16*)alloc((size_t)SS * DD * 2);
  float* hbuf  = (float*)alloc((size_t)SS * DD * 4);
  float* hf    = (float*)alloc((size_t)SS * DD * 4);
  u16* hf16    = (u16*)alloc((size_t)SS * DD * 2);
  u16* kT      = (u16*)alloc((size_t)NKVH * SS * HDIM * 2);
  u16* vT2     = (u16*)alloc((size_t)NKVH * HDIM * SS * 2);
  u16* wqkv16  = (u16*)alloc((size_t)QKVN * DD * 2);
  u16* wo16    = (u16*)alloc((size_t)DD * DD * 2);
  u16* w1_16   = (u16*)alloc((size_t)NE * NI * DD * 2);
  u16* w3_16   = (u16*)alloc((size_t)NE * NI * DD * 2);
  u16* w2_16   = (u16*)alloc((size_t)NE * DD * NI * 2);
  u16* xslot   = (u16*)alloc((size_t)PCAP * DD * 2);
  u16* x13     = (u16*)alloc((size_t)PCAP * NI * 2);
  float* pbuf  = (float*)alloc((size_t)2 * PCAP * DD * 4);
  int* ei      = (int*)alloc((size_t)SS * 2 * 4);
  float* ew    = (float*)alloc((size_t)SS * 2 * 4);
  int* slot_of = (int*)alloc((size_t)SS * 2 * 4);
  int* cnt     = (int*)alloc(NE * 4);
  int* poff    = (int*)alloc((NE + 1) * 4);
  int* fill    = (int*)alloc(NE * 4);
  int* tmap    = (int*)alloc((NTILEMAX + 1) * 4);
  u16* qT      = hn16;

  auto conv = [&](const float* src, u16* dst, size_t n) {
    int n4 = (int)(n / 4);
    f32_to_bf16_kernel<<<(n4 + 255) / 256, 256, 0, stream>>>(src, dst, n4);
  };

  zero_cnt_kernel<<<1, 64, 0, stream>>>(cnt);
  conv(wqkv, wqkv16, (size_t)QKVN * DD);
  conv(wo, wo16, (size_t)DD * DD);
  conv(w1, w1_16, (size_t)NE * NI * DD);
  conv(w3, w3_16, (size_t)NE * NI * DD);
  conv(w2, w2_16, (size_t)NE * DD * NI);

  // ---- attention path ----
  rmsnorm_kernel<<<SS, 256, 0, stream>>>(x, attn_norm_w, nullptr, hn16);
  gemm128<<<dim3(SS / 128, QKVN / 128), 256, 0, stream>>>(hn16, wqkv16, qkv, nullptr, QKVN, DD);
  rope_kernel<<<SS, 256, 0, stream>>>(qkv, freqs, qT, kT);
  vtrans_kernel<<<dim3(SS / 64, 4), 256, 0, stream>>>(qkv, vT2);
  attn_flash<<<dim3(SS / BQ, NH), 256, 0, stream>>>(qT, kT, vT2, y16);
  gemm128<<<dim3(SS / 128, DD / 128), 256, 0, stream>>>(y16, wo16, hbuf, x, DD, DD);

  // ---- MoE path ----
  rmsnorm_kernel<<<SS, 256, 0, stream>>>(hbuf, ffn_norm_w, hf, hf16);
  gate_kernel<<<SS, 64, 0, stream>>>(hf, gate_w, ei, ew, cnt);
  prefix_kernel<<<1, 64, 0, stream>>>(cnt, poff, fill);
  tilemap_kernel<<<1, 64, 0, stream>>>(poff, tmap);
  fill_kernel<<<(SS + 255) / 256, 256, 0, stream>>>(ei, poff, fill, slot_of);
  gather_kernel<<<SS, 256, 0, stream>>>(hf16, slot_of, xslot);
  moe_stage1<<<dim3(NTILEMAX, NI / 64), 256, 0, stream>>>(xslot, w1_16, w3_16, tmap, x13);
  moe_stage2<<<dim3(NTILEMAX, 16), 256, 0, stream>>>(x13, w2_16, tmap, pbuf);
  final_kernel<<<SS, 256, 0, stream>>>(hbuf, pbuf, pbuf + (size_t)PCAP * DD, slot_of, ew, out);
}

// Round 2
// 797.644 us; speedup vs baseline: 1.1126x; 1.0203x over previous
//
#include <hip/hip_runtime.h>
#include <hip/hip_bf16.h>
#include <math.h>

#define SS 2048
#define DD 1024
#define NH 16
#define NKVH 4
#define HDIM 64
#define NE 8
#define NI 3584
#define QKVN 1536
#define PCAP 5120
#define NTILEMAX 40   // PCAP/128

typedef unsigned short u16;
typedef short short8 __attribute__((ext_vector_type(8)));
typedef float floatx4 __attribute__((ext_vector_type(4)));

__device__ inline u16 f2bf(float f) {
  unsigned u = __float_as_uint(f);
  unsigned r = u + 0x7fffu + ((u >> 16) & 1u);
  return (u16)(r >> 16);
}
__device__ inline float bf2f(u16 h) { return __uint_as_float((unsigned)h << 16); }

// ---------------- fp32 -> bf16 bulk convert ----------------
__global__ void f32_to_bf16_kernel(const float* __restrict__ in, u16* __restrict__ out, int n4) {
  int i = blockIdx.x * 256 + threadIdx.x;
  if (i >= n4) return;
  float4 v = ((const float4*)in)[i];
  ((ushort4*)out)[i] = make_ushort4(f2bf(v.x), f2bf(v.y), f2bf(v.z), f2bf(v.w));
}

// ---------------- RMSNorm ----------------
__global__ void rmsnorm_kernel(const float* __restrict__ x, const float* __restrict__ w,
                               float* __restrict__ o32, u16* __restrict__ o16) {
  int row = blockIdx.x;
  int t = threadIdx.x;
  float4 v = ((const float4*)(x + (size_t)row * DD))[t];
  float ss = v.x * v.x + v.y * v.y + v.z * v.z + v.w * v.w;
  for (int o = 32; o > 0; o >>= 1) ss += __shfl_xor(ss, o);
  __shared__ float red[4];
  if ((t & 63) == 0) red[t >> 6] = ss;
  __syncthreads();
  float tot = red[0] + red[1] + red[2] + red[3];
  float r = rsqrtf(tot * (1.f / DD) + 1e-5f);
  float4 wv = ((const float4*)w)[t];
  float4 o;
  o.x = v.x * r * wv.x; o.y = v.y * r * wv.y; o.z = v.z * r * wv.z; o.w = v.w * r * wv.w;
  if (o32) ((float4*)(o32 + (size_t)row * DD))[t] = o;
  if (o16) ((ushort4*)(o16 + (size_t)row * DD))[t] =
      make_ushort4(f2bf(o.x), f2bf(o.y), f2bf(o.z), f2bf(o.w));
}

// ---------------- Plain MFMA GEMM (qkv, wo): C = A @ B^T (+addend) ----------------
__global__ __launch_bounds__(256) void gemm128(
    const u16* __restrict__ A, const u16* __restrict__ B,
    float* __restrict__ C, const float* __restrict__ addend, int N, int K) {
  __shared__ u16 As[128 * 32];
  __shared__ u16 Bs[128 * 32];
  int tid = threadIdx.x;
  int bm = blockIdx.x * 128;
  int bn = blockIdx.y * 128;
  const u16* Ag = A + (size_t)bm * K;
  const u16* Bg = B + (size_t)bn * K;
  int wave = tid >> 6, lane = tid & 63;
  int wm = wave >> 1, wn = wave & 1;
  int ml = lane & 15, quad = lane >> 4;

  floatx4 acc[4][4];
#pragma unroll
  for (int i = 0; i < 4; i++)
#pragma unroll
    for (int j = 0; j < 4; j++) acc[i][j] = (floatx4){0.f, 0.f, 0.f, 0.f};

  for (int k0 = 0; k0 < K; k0 += 32) {
#pragma unroll
    for (int r = 0; r < 2; r++) {
      int s = tid + r * 256;
      int row = s >> 2, kc = (s & 3) * 8;
      __builtin_amdgcn_global_load_lds(
          (const __attribute__((address_space(1))) unsigned*)(Ag + (size_t)row * K + k0 + kc),
          (__attribute__((address_space(3))) unsigned*)(As + s * 8), 16, 0, 0);
      __builtin_amdgcn_global_load_lds(
          (const __attribute__((address_space(1))) unsigned*)(Bg + (size_t)row * K + k0 + kc),
          (__attribute__((address_space(3))) unsigned*)(Bs + s * 8), 16, 0, 0);
    }
    __syncthreads();
    short8 a[4], b[4];
#pragma unroll
    for (int i = 0; i < 4; i++)
      a[i] = *(const short8*)(As + ((wm * 64 + i * 16 + ml) * 32 + quad * 8));
#pragma unroll
    for (int j = 0; j < 4; j++)
      b[j] = *(const short8*)(Bs + ((wn * 64 + j * 16 + ml) * 32 + quad * 8));
#pragma unroll
    for (int i = 0; i < 4; i++)
#pragma unroll
      for (int j = 0; j < 4; j++)
        acc[i][j] = __builtin_amdgcn_mfma_f32_16x16x32_bf16(a[i], b[j], acc[i][j], 0, 0, 0);
    __syncthreads();
  }
#pragma unroll
  for (int i = 0; i < 4; i++) {
#pragma unroll
    for (int j = 0; j < 4; j++) {
#pragma unroll
      for (int r = 0; r < 4; r++) {
        int row = bm + wm * 64 + i * 16 + quad * 4 + r;
        int col = bn + wn * 64 + j * 16 + ml;
        size_t idx = (size_t)row * N + col;
        float v = acc[i][j][r];
        if (addend) v += addend[idx];
        C[idx] = v;
      }
    }
  }
}

// ---------------- MoE stage 1 fused: x13 = silu(X@w1^T) * (X@w3^T), bf16 out ----------------
// 128(M)x64(N) tile, 60 VGPR (round 1: 195->116us).
// Round 2: XCD-affinity block remap. Grid (8, 280):
//   tile = y % 40 (fast along y), col = x + 8*(y/40).
// Blocks sharing a (expert,col) weight slice differ by flat stride 8 ->
// same XCD residue, adjacent in time -> w1/w3 slice filled into ONE L2
// and reused by the ~5 row-tiles (was: 5 flat-adjacent blocks on 5
// different XCDs -> ~5x L2 fills, FETCH 270MB vs 128MB unique).
__global__ __launch_bounds__(256, 3) void moe_stage1(
    const u16* __restrict__ xslot, const u16* __restrict__ w1b, const u16* __restrict__ w3b,
    const int* __restrict__ tmap, u16* __restrict__ x13) {
  __shared__ u16 As[128 * 32];
  __shared__ u16 B1s[64 * 32];
  __shared__ u16 B3s[64 * 32];
  int tI = blockIdx.y % NTILEMAX;
  int cI = blockIdx.x + 8 * (blockIdx.y / NTILEMAX);
  if (tI >= tmap[0]) return;
  int entry = tmap[1 + tI];
  int e = entry & 7;
  int row0 = (entry >> 3) * 128;
  int bn = cI * 64;
  const u16* Ag = xslot + (size_t)row0 * DD;
  const u16* B1g = w1b + (size_t)e * NI * DD + (size_t)bn * DD;
  const u16* B3g = w3b + (size_t)e * NI * DD + (size_t)bn * DD;
  int tid = threadIdx.x, wave = tid >> 6, lane = tid & 63;
  int wm = wave >> 1, wn = wave & 1;
  int ml = lane & 15, quad = lane >> 4;

  floatx4 acc1[4][2], acc3[4][2];
#pragma unroll
  for (int i = 0; i < 4; i++)
#pragma unroll
    for (int j = 0; j < 2; j++) {
      acc1[i][j] = (floatx4){0.f, 0.f, 0.f, 0.f};
      acc3[i][j] = (floatx4){0.f, 0.f, 0.f, 0.f};
    }

  for (int k0 = 0; k0 < DD; k0 += 32) {
#pragma unroll
    for (int r = 0; r < 2; r++) {
      int s = tid + r * 256;
      int row = s >> 2, kc = (s & 3) * 8;
      __builtin_amdgcn_global_load_lds(
          (const __attribute__((address_space(1))) unsigned*)(Ag + (size_t)row * DD + k0 + kc),
          (__attribute__((address_space(3))) unsigned*)(As + s * 8), 16, 0, 0);
    }
    {
      int row = tid >> 2, kc = (tid & 3) * 8;
      __builtin_amdgcn_global_load_lds(
          (const __attribute__((address_space(1))) unsigned*)(B1g + (size_t)row * DD + k0 + kc),
          (__attribute__((address_space(3))) unsigned*)(B1s + tid * 8), 16, 0, 0);
      __builtin_amdgcn_global_load_lds(
          (const __attribute__((address_space(1))) unsigned*)(B3g + (size_t)row * DD + k0 + kc),
          (__attribute__((address_space(3))) unsigned*)(B3s + tid * 8), 16, 0, 0);
    }
    __syncthreads();
    short8 a[4], b1[2], b3[2];
#pragma unroll
    for (int i = 0; i < 4; i++)
      a[i] = *(const short8*)(As + ((wm * 64 + i * 16 + ml) * 32 + quad * 8));
#pragma unroll
    for (int j = 0; j < 2; j++) {
      b1[j] = *(const short8*)(B1s + ((wn * 32 + j * 16 + ml) * 32 + quad * 8));
      b3[j] = *(const short8*)(B3s + ((wn * 32 + j * 16 + ml) * 32 + quad * 8));
    }
#pragma unroll
    for (int i = 0; i < 4; i++)
#pragma unroll
      for (int j = 0; j < 2; j++) {
        acc1[i][j] = __builtin_amdgcn_mfma_f32_16x16x32_bf16(a[i], b1[j], acc1[i][j], 0, 0, 0);
        acc3[i][j] = __builtin_amdgcn_mfma_f32_16x16x32_bf16(a[i], b3[j], acc3[i][j], 0, 0, 0);
      }
    __syncthreads();
  }
#pragma unroll
  for (int i = 0; i < 4; i++) {
#pragma unroll
    for (int j = 0; j < 2; j++) {
#pragma unroll
      for (int r = 0; r < 4; r++) {
        int row = row0 + wm * 64 + i * 16 + quad * 4 + r;
        int col = bn + wn * 32 + j * 16 + ml;
        float v1 = acc1[i][j][r], v3 = acc3[i][j][r];
        float sil = v1 / (1.f + __expf(-v1));
        x13[(size_t)row * NI + col] = f2bf(sil * v3);
      }
    }
  }
}

// ---------------- MoE stage 2 split-K=2: pbuf[kh] = x13 @ w2^T (fp32 partials) ----------------
// Round 2: same XCD-affinity remap. Grid (8, 80): nt = x, tile = y%40, kh = y/40.
// Same (expert,nt,kh) w2 slice across ~5 tiles -> flat stride 8 -> one L2 fill.
__global__ __launch_bounds__(256) void moe_stage2(
    const u16* __restrict__ x13, const u16* __restrict__ w2b,
    const int* __restrict__ tmap, float* __restrict__ pbuf) {
  __shared__ u16 As[128 * 32];
  __shared__ u16 Bs[128 * 32];
  int tI = blockIdx.y % NTILEMAX;
  int kh = blockIdx.y / NTILEMAX;
  int nt = blockIdx.x;
  if (tI >= tmap[0]) return;
  int entry = tmap[1 + tI];
  int e = entry & 7;
  int row0 = (entry >> 3) * 128;
  int bn = nt * 128;
  int kbeg = kh * (NI / 2), kend = kbeg + NI / 2;
  const u16* Ag = x13 + (size_t)row0 * NI;
  const u16* Bg = w2b + (size_t)e * DD * NI + (size_t)bn * NI;
  float* Cp = pbuf + (size_t)kh * PCAP * DD;
  int tid = threadIdx.x, wave = tid >> 6, lane = tid & 63;
  int wm = wave >> 1, wn = wave & 1;
  int ml = lane & 15, quad = lane >> 4;

  floatx4 acc[4][4];
#pragma unroll
  for (int i = 0; i < 4; i++)
#pragma unroll
    for (int j = 0; j < 4; j++) acc[i][j] = (floatx4){0.f, 0.f, 0.f, 0.f};

  for (int k0 = kbeg; k0 < kend; k0 += 32) {
#pragma unroll
    for (int r = 0; r < 2; r++) {
      int s = tid + r * 256;
      int row = s >> 2, kc = (s & 3) * 8;
      __builtin_amdgcn_global_load_lds(
          (const __attribute__((address_space(1))) unsigned*)(Ag + (size_t)row * NI + k0 + kc),
          (__attribute__((address_space(3))) unsigned*)(As + s * 8), 16, 0, 0);
      __builtin_amdgcn_global_load_lds(
          (const __attribute__((address_space(1))) unsigned*)(Bg + (size_t)row * NI + k0 + kc),
          (__attribute__((address_space(3))) unsigned*)(Bs + s * 8), 16, 0, 0);
    }
    __syncthreads();
    short8 a[4], b[4];
#pragma unroll
    for (int i = 0; i < 4; i++)
      a[i] = *(const short8*)(As + ((wm * 64 + i * 16 + ml) * 32 + quad * 8));
#pragma unroll
    for (int j = 0; j < 4; j++)
      b[j] = *(const short8*)(Bs + ((wn * 64 + j * 16 + ml) * 32 + quad * 8));
#pragma unroll
    for (int i = 0; i < 4; i++)
#pragma unroll
      for (int j = 0; j < 4; j++)
        acc[i][j] = __builtin_amdgcn_mfma_f32_16x16x32_bf16(a[i], b[j], acc[i][j], 0, 0, 0);
    __syncthreads();
  }
#pragma unroll
  for (int i = 0; i < 4; i++) {
#pragma unroll
    for (int j = 0; j < 4; j++) {
#pragma unroll
      for (int r = 0; r < 4; r++) {
        int row = row0 + wm * 64 + i * 16 + quad * 4 + r;
        int col = bn + wn * 64 + j * 16 + ml;
        Cp[(size_t)row * DD + col] = acc[i][j][r];
      }
    }
  }
}

// ---------------- RoPE: fp32 qkv -> bf16 qT [NH][S][64] (scaled 1/8), kT [NKVH][S][64] ----------------
__global__ void rope_kernel(const float* __restrict__ qkv, const float* __restrict__ freqs,
                            u16* __restrict__ qT, u16* __restrict__ kT) {
  int s = blockIdx.x;
  int tid = threadIdx.x;
#pragma unroll
  for (int r = 0; r < 2; r++) {
    int tt = r * 256 + tid;
    int hh = tt >> 5, i = tt & 31;
    const float* p = qkv + (size_t)s * QKVN + hh * 64 + 2 * i;
    float c = freqs[(s * 32 + i) * 2], sn = freqs[(s * 32 + i) * 2 + 1];
    float x0 = p[0], x1 = p[1];
    float r0 = (x0 * c - x1 * sn) * 0.125f;
    float r1 = (x1 * c + x0 * sn) * 0.125f;
    unsigned pk = (unsigned)f2bf(r0) | ((unsigned)f2bf(r1) << 16);
    *(unsigned*)(qT + ((size_t)hh * SS + s) * 64 + 2 * i) = pk;
  }
  if (tid < 128) {
    int hh = tid >> 5, i = tid & 31;
    const float* p = qkv + (size_t)s * QKVN + DD + hh * 64 + 2 * i;
    float c = freqs[(s * 32 + i) * 2], sn = freqs[(s * 32 + i) * 2 + 1];
    float x0 = p[0], x1 = p[1];
    float r0 = x0 * c - x1 * sn;
    float r1 = x1 * c + x0 * sn;
    unsigned pk = (unsigned)f2bf(r0) | ((unsigned)f2bf(r1) << 16);
    *(unsigned*)(kT + ((size_t)hh * SS + s) * 64 + 2 * i) = pk;
  }
}

// ---------------- V transpose: qkv v-part -> vT2 [NKVH*64][S] bf16 ----------------
__global__ void vtrans_kernel(const float* __restrict__ qkv, u16* __restrict__ vT2) {
  __shared__ u16 tile[64][65];
  int bs = blockIdx.x * 64;
  int bc = blockIdx.y * 64;
  int tid = threadIdx.x;
#pragma unroll
  for (int it = 0; it < 4; it++) {
    int idx = it * 256 + tid;
    int r = idx >> 4, c4 = idx & 15;
    float4 v = *(const float4*)(qkv + (size_t)(bs + r) * QKVN + DD + 256 + bc + c4 * 4);
    tile[r][c4 * 4 + 0] = f2bf(v.x);
    tile[r][c4 * 4 + 1] = f2bf(v.y);
    tile[r][c4 * 4 + 2] = f2bf(v.z);
    tile[r][c4 * 4 + 3] = f2bf(v.w);
  }
  __syncthreads();
#pragma unroll
  for (int it = 0; it < 4; it++) {
    int idx = it * 256 + tid;
    int cc = idx >> 4, s4 = idx & 15;
    ushort4 o = make_ushort4(tile[s4 * 4 + 0][cc], tile[s4 * 4 + 1][cc],
                             tile[s4 * 4 + 2][cc], tile[s4 * 4 + 3][cc]);
    *(ushort4*)(vT2 + (size_t)(bc + cc) * SS + bs + s4 * 4) = o;
  }
}

// ---------------- Flash attention: BQ=128 (4 waves x 32 rows), BKV=64, MFMA ----------------
#define BQ 128
#define BKV 64
__global__ __launch_bounds__(256) void attn_flash(const u16* __restrict__ qT,
                                                  const u16* __restrict__ kT,
                                                  const u16* __restrict__ vT2,
                                                  u16* __restrict__ y) {
  __shared__ u16 Ks[2 * 64 * 32];
  __shared__ u16 Vs[2 * 64 * 32];
  __shared__ u16 Ps[2 * 128 * 36];
  int t = blockIdx.x;
  int h = blockIdx.y;
  int kvh = h >> 2;
  int bq = t * BQ;
  int tid = threadIdx.x, wave = tid >> 6, lane = tid & 63;
  int ml = lane & 15, quad = lane >> 4;

  short8 qf[2][2];
#pragma unroll
  for (int i = 0; i < 2; i++)
#pragma unroll
    for (int c = 0; c < 2; c++)
      qf[i][c] = *(const short8*)(qT + ((size_t)h * SS + bq + wave * 32 + i * 16 + ml) * 64 +
                                  c * 32 + quad * 8);

  float m_i[2][4], l_i[2][4];
  floatx4 o_acc[2][4];
#pragma unroll
  for (int i = 0; i < 2; i++)
#pragma unroll
    for (int r = 0; r < 4; r++) {
      m_i[i][r] = -1e30f;
      l_i[i][r] = 0.f;
      o_acc[i][r] = (floatx4){0.f, 0.f, 0.f, 0.f};
    }

  int nkv = 2 * t + 2;
  for (int kt = 0; kt < nkv; kt++) {
    int bk = kt * BKV;
    __syncthreads();
#pragma unroll
    for (int r = 0; r < 2; r++) {
      int ch = r * 256 + tid;
      int c = ch >> 8, srow = (ch >> 2) & 63, o8 = ch & 3;
      __builtin_amdgcn_global_load_lds(
          (const __attribute__((address_space(1))) unsigned*)(
              kT + ((size_t)kvh * SS + bk + srow) * 64 + c * 32 + o8 * 8),
          (__attribute__((address_space(3))) unsigned*)(Ks + ch * 8), 16, 0, 0);
      __builtin_amdgcn_global_load_lds(
          (const __attribute__((address_space(1))) unsigned*)(
              vT2 + ((size_t)kvh * 64 + srow) * SS + bk + c * 32 + o8 * 8),
          (__attribute__((address_space(3))) unsigned*)(Vs + ch * 8), 16, 0, 0);
    }
    __syncthreads();

    floatx4 s_acc[2][4];
#pragma unroll
    for (int i = 0; i < 2; i++)
#pragma unroll
      for (int j = 0; j < 4; j++) s_acc[i][j] = (floatx4){0.f, 0.f, 0.f, 0.f};
#pragma unroll
    for (int c = 0; c < 2; c++) {
#pragma unroll
      for (int jk = 0; jk < 4; jk++) {
        short8 kf = *(const short8*)(Ks + c * 2048 + (jk * 16 + ml) * 32 + quad * 8);
#pragma unroll
        for (int i = 0; i < 2; i++)
          s_acc[i][jk] = __builtin_amdgcn_mfma_f32_16x16x32_bf16(qf[i][c], kf, s_acc[i][jk], 0, 0, 0);
      }
    }
    if (bk + BKV - 1 > bq) {
#pragma unroll
      for (int i = 0; i < 2; i++)
#pragma unroll
        for (int jk = 0; jk < 4; jk++)
#pragma unroll
          for (int r = 0; r < 4; r++) {
            int row = bq + wave * 32 + i * 16 + quad * 4 + r;
            int col = bk + jk * 16 + ml;
            if (col > row) s_acc[i][jk][r] = -1e30f;
          }
    }
#pragma unroll
    for (int i = 0; i < 2; i++) {
#pragma unroll
      for (int r = 0; r < 4; r++) {
        float mx = -1e30f;
#pragma unroll
        for (int jk = 0; jk < 4; jk++) mx = fmaxf(mx, s_acc[i][jk][r]);
        for (int o = 1; o < 16; o <<= 1) mx = fmaxf(mx, __shfl_xor(mx, o));
        float mnew = fmaxf(m_i[i][r], mx);
        float alpha = __expf(m_i[i][r] - mnew);
        m_i[i][r] = mnew;
        float rs = 0.f;
#pragma unroll
        for (int jk = 0; jk < 4; jk++) {
          float p = __expf(s_acc[i][jk][r] - mnew);
          s_acc[i][jk][r] = p;
          rs += p;
        }
        for (int o = 1; o < 16; o <<= 1) rs += __shfl_xor(rs, o);
        l_i[i][r] = l_i[i][r] * alpha + rs;
#pragma unroll
        for (int jd = 0; jd < 4; jd++) o_acc[i][jd][r] *= alpha;
      }
    }
#pragma unroll
    for (int i = 0; i < 2; i++)
#pragma unroll
      for (int jk = 0; jk < 4; jk++)
#pragma unroll
        for (int r = 0; r < 4; r++) {
          int row = wave * 32 + i * 16 + quad * 4 + r;
          int col = jk * 16 + ml;
          Ps[(col >> 5) * (128 * 36) + row * 36 + (col & 31)] = f2bf(s_acc[i][jk][r]);
        }
#pragma unroll
    for (int kc = 0; kc < 2; kc++) {
      short8 pf[2];
#pragma unroll
      for (int i = 0; i < 2; i++)
        pf[i] = *(const short8*)(Ps + kc * (128 * 36) + (wave * 32 + i * 16 + ml) * 36 + quad * 8);
#pragma unroll
      for (int jd = 0; jd < 4; jd++) {
        short8 vf = *(const short8*)(Vs + kc * 2048 + (jd * 16 + ml) * 32 + quad * 8);
#pragma unroll
        for (int i = 0; i < 2; i++)
          o_acc[i][jd] = __builtin_amdgcn_mfma_f32_16x16x32_bf16(pf[i], vf, o_acc[i][jd], 0, 0, 0);
      }
    }
  }
#pragma unroll
  for (int i = 0; i < 2; i++) {
    float inv[4];
#pragma unroll
    for (int r = 0; r < 4; r++) inv[r] = 1.f / l_i[i][r];
#pragma unroll
    for (int jd = 0; jd < 4; jd++)
#pragma unroll
      for (int r = 0; r < 4; r++) {
        int row = bq + wave * 32 + i * 16 + quad * 4 + r;
        int col = h * 64 + jd * 16 + ml;
        y[(size_t)row * DD + col] = f2bf(o_acc[i][jd][r] * inv[r]);
      }
  }
}

// ---------------- Gate ----------------
__global__ __launch_bounds__(64) void gate_kernel(const float* __restrict__ hf,
                                                  const float* __restrict__ gw,
                                                  int* __restrict__ ei, float* __restrict__ ew,
                                                  int* __restrict__ cnt) {
  int t = blockIdx.x;
  int lane = threadIdx.x;
  const float* xr = hf + (size_t)t * DD;
  float acc[NE] = {};
  for (int c = 0; c < DD / 64; c++) {
    float xv = xr[lane + 64 * c];
#pragma unroll
    for (int e = 0; e < NE; e++) acc[e] += xv * gw[e * DD + lane + 64 * c];
  }
#pragma unroll
  for (int e = 0; e < NE; e++)
    for (int o = 32; o > 0; o >>= 1) acc[e] += __shfl_xor(acc[e], o);
  if (lane == 0) {
    float mx = acc[0];
    for (int e = 1; e < NE; e++) mx = fmaxf(mx, acc[e]);
    float p[NE], sum = 0.f;
    for (int e = 0; e < NE; e++) { p[e] = __expf(acc[e] - mx); sum += p[e]; }
    for (int e = 0; e < NE; e++) p[e] /= sum;
    int i0 = 0;
    for (int e = 1; e < NE; e++) if (p[e] > p[i0]) i0 = e;
    int i1 = (i0 == 0) ? 1 : 0;
    for (int e = 0; e < NE; e++) if (e != i0 && p[e] > p[i1]) i1 = e;
    float w0 = p[i0], w1 = p[i1], s = w0 + w1;
    ei[t * 2] = i0; ei[t * 2 + 1] = i1;
    ew[t * 2] = w0 / s; ew[t * 2 + 1] = w1 / s;
    atomicAdd(&cnt[i0], 1);
    atomicAdd(&cnt[i1], 1);
  }
}

__global__ void zero_cnt_kernel(int* cnt) {
  if (threadIdx.x < NE) cnt[threadIdx.x] = 0;
}

__global__ void prefix_kernel(const int* __restrict__ cnt, int* __restrict__ poff,
                              int* __restrict__ fill) {
  if (threadIdx.x == 0) {
    int pacc = 0;
    for (int e = 0; e < NE; e++) {
      poff[e] = pacc;
      pacc += (cnt[e] + 127) & ~127;
    }
    poff[NE] = pacc;
  }
  if (threadIdx.x < NE) fill[threadIdx.x] = 0;
}

// tmap[0] = ntiles, tmap[1+i] = (rowoff128 << 3) | expert
__global__ void tilemap_kernel(const int* __restrict__ poff, int* __restrict__ tmap) {
  if (threadIdx.x == 0) {
    int n = 0;
    for (int e = 0; e < NE; e++) {
      int r0 = poff[e] >> 7, r1 = poff[e + 1] >> 7;
      for (int r = r0; r < r1; r++) tmap[1 + n++] = (r << 3) | e;
    }
    tmap[0] = n;
  }
}

__global__ void fill_kernel(const int* __restrict__ ei, const int* __restrict__ poff,
                            int* __restrict__ fill, int* __restrict__ slot_of) {
  int t = blockIdx.x * blockDim.x + threadIdx.x;
  if (t >= SS) return;
  for (int a = 0; a < 2; a++) {
    int e = ei[t * 2 + a];
    int pos = atomicAdd(&fill[e], 1);
    slot_of[t * 2 + a] = poff[e] + pos;
  }
}

__global__ void gather_kernel(const u16* __restrict__ hf16, const int* __restrict__ slot_of,
                              u16* __restrict__ xslot) {
  int t = blockIdx.x;
  uint2 v = ((const uint2*)(hf16 + (size_t)t * DD))[threadIdx.x];
  for (int a = 0; a < 2; a++) {
    int slot = slot_of[t * 2 + a];
    ((uint2*)(xslot + (size_t)slot * DD))[threadIdx.x] = v;
  }
}

// out = h + w0*(p0[s0]+p1[s0]) + w1*(p0[s1]+p1[s1])
__global__ void final_kernel(const float* __restrict__ h, const float* __restrict__ p0,
                             const float* __restrict__ p1, const int* __restrict__ slot_of,
                             const float* __restrict__ ew, float* __restrict__ out) {
  int t = blockIdx.x;
  int s0 = slot_of[t * 2], s1 = slot_of[t * 2 + 1];
  float w0 = ew[t * 2], w1 = ew[t * 2 + 1];
  float4 hv = ((const float4*)(h + (size_t)t * DD))[threadIdx.x];
  float4 a0 = ((const float4*)(p0 + (size_t)s0 * DD))[threadIdx.x];
  float4 a1 = ((const float4*)(p1 + (size_t)s0 * DD))[threadIdx.x];
  float4 b0 = ((const float4*)(p0 + (size_t)s1 * DD))[threadIdx.x];
  float4 b1 = ((const float4*)(p1 + (size_t)s1 * DD))[threadIdx.x];
  float4 o;
  o.x = hv.x + w0 * (a0.x + a1.x) + w1 * (b0.x + b1.x);
  o.y = hv.y + w0 * (a0.y + a1.y) + w1 * (b0.y + b1.y);
  o.z = hv.z + w0 * (a0.z + a1.z) + w1 * (b0.z + b1.z);
  o.w = hv.w + w0 * (a0.w + a1.w) + w1 * (b0.w + b1.w);
  ((float4*)(out + (size_t)t * DD))[threadIdx.x] = o;
}

extern "C" void kernel_launch(void* const* d_in, const int* in_sizes, int n_in,
                              void* d_out, int out_size, void* d_ws, size_t ws_size,
                              hipStream_t stream) {
  const float* x = (const float*)d_in[0];
  const float* wqkv = (const float*)d_in[1];
  const float* wo = (const float*)d_in[2];
  const float* gate_w = (const float*)d_in[3];
  const float* w1 = (const float*)d_in[4];
  const float* w2 = (const float*)d_in[5];
  const float* w3 = (const float*)d_in[6];
  const float* attn_norm_w = (const float*)d_in[7];
  const float* ffn_norm_w = (const float*)d_in[8];
  const float* freqs = (const float*)d_in[9];
  float* out = (float*)d_out;

  char* ws = (char*)d_ws;
  size_t off = 0;
  auto alloc = [&](size_t bytes) -> char* {
    char* p = ws + off;
    off = (off + bytes + 255) & ~(size_t)255;
    return p;
  };
  u16* hn16    = (u16*)alloc((size_t)SS * DD * 2);   // aliased as qT after qkv GEMM
  float* qkv   = (float*)alloc((size_t)SS * QKVN * 4);
  u16* y16     = (u16*)alloc((size_t)SS * DD * 2);
  float* hbuf  = (float*)alloc((size_t)SS * DD * 4);
  float* hf    = (float*)alloc((size_t)SS * DD * 4);
  u16* hf16    = (u16*)alloc((size_t)SS * DD * 2);
  u16* kT      = (u16*)alloc((size_t)NKVH * SS * HDIM * 2);
  u16* vT2     = (u16*)alloc((size_t)NKVH * HDIM * SS * 2);
  u16* wqkv16  = (u16*)alloc((size_t)QKVN * DD * 2);
  u16* wo16    = (u16*)alloc((size_t)DD * DD * 2);
  u16* w1_16   = (u16*)alloc((size_t)NE * NI * DD * 2);
  u16* w3_16   = (u16*)alloc((size_t)NE * NI * DD * 2);
  u16* w2_16   = (u16*)alloc((size_t)NE * DD * NI * 2);
  u16* xslot   = (u16*)alloc((size_t)PCAP * DD * 2);
  u16* x13     = (u16*)alloc((size_t)PCAP * NI * 2);
  float* pbuf  = (float*)alloc((size_t)2 * PCAP * DD * 4);
  int* ei      = (int*)alloc((size_t)SS * 2 * 4);
  float* ew    = (float*)alloc((size_t)SS * 2 * 4);
  int* slot_of = (int*)alloc((size_t)SS * 2 * 4);
  int* cnt     = (int*)alloc(NE * 4);
  int* poff    = (int*)alloc((NE + 1) * 4);
  int* fill    = (int*)alloc(NE * 4);
  int* tmap    = (int*)alloc((NTILEMAX + 1) * 4);
  u16* qT      = hn16;

  auto conv = [&](const float* src, u16* dst, size_t n) {
    int n4 = (int)(n / 4);
    f32_to_bf16_kernel<<<(n4 + 255) / 256, 256, 0, stream>>>(src, dst, n4);
  };

  zero_cnt_kernel<<<1, 64, 0, stream>>>(cnt);
  conv(wqkv, wqkv16, (size_t)QKVN * DD);
  conv(wo, wo16, (size_t)DD * DD);
  conv(w1, w1_16, (size_t)NE * NI * DD);
  conv(w3, w3_16, (size_t)NE * NI * DD);
  conv(w2, w2_16, (size_t)NE * DD * NI);

  // ---- attention path ----
  rmsnorm_kernel<<<SS, 256, 0, stream>>>(x, attn_norm_w, nullptr, hn16);
  gemm128<<<dim3(SS / 128, QKVN / 128), 256, 0, stream>>>(hn16, wqkv16, qkv, nullptr, QKVN, DD);
  rope_kernel<<<SS, 256, 0, stream>>>(qkv, freqs, qT, kT);
  vtrans_kernel<<<dim3(SS / 64, 4), 256, 0, stream>>>(qkv, vT2);
  attn_flash<<<dim3(SS / BQ, NH), 256, 0, stream>>>(qT, kT, vT2, y16);
  gemm128<<<dim3(SS / 128, DD / 128), 256, 0, stream>>>(y16, wo16, hbuf, x, DD, DD);

  // ---- MoE path ----
  rmsnorm_kernel<<<SS, 256, 0, stream>>>(hbuf, ffn_norm_w, hf, hf16);
  gate_kernel<<<SS, 64, 0, stream>>>(hf, gate_w, ei, ew, cnt);
  prefix_kernel<<<1, 64, 0, stream>>>(cnt, poff, fill);
  tilemap_kernel<<<1, 64, 0, stream>>>(poff, tmap);
  fill_kernel<<<(SS + 255) / 256, 256, 0, stream>>>(ei, poff, fill, slot_of);
  gather_kernel<<<SS, 256, 0, stream>>>(hf16, slot_of, xslot);
  // XCD-affinity grids (see kernel comments): (8, 7*40) and (8, 2*40)
  moe_stage1<<<dim3(8, (NI / 64 / 8) * NTILEMAX), 256, 0, stream>>>(xslot, w1_16, w3_16, tmap, x13);
  moe_stage2<<<dim3(8, 2 * NTILEMAX), 256, 0, stream>>>(x13, w2_16, tmap, pbuf);
  final_kernel<<<SS, 256, 0, stream>>>(hbuf, pbuf, pbuf + (size_t)PCAP * DD, slot_of, ew, out);
}

// Round 4
// 762.159 us; speedup vs baseline: 1.1644x; 1.0466x over previous
//
#include <hip/hip_runtime.h>
#include <hip/hip_bf16.h>
#include <math.h>

#define SS 2048
#define DD 1024
#define NH 16
#define NKVH 4
#define HDIM 64
#define NE 8
#define NI 3584
#define QKVN 1536
#define PCAP 5120
#define NTILEMAX 40   // PCAP/128

typedef unsigned short u16;
typedef short short8 __attribute__((ext_vector_type(8)));
typedef float floatx4 __attribute__((ext_vector_type(4)));

__device__ inline u16 f2bf(float f) {
  unsigned u = __float_as_uint(f);
  unsigned r = u + 0x7fffu + ((u >> 16) & 1u);
  return (u16)(r >> 16);
}
__device__ inline float bf2f(u16 h) { return __uint_as_float((unsigned)h << 16); }

// ---------------- fp32 -> bf16 bulk convert ----------------
__global__ void f32_to_bf16_kernel(const float* __restrict__ in, u16* __restrict__ out, int n4) {
  int i = blockIdx.x * 256 + threadIdx.x;
  if (i >= n4) return;
  float4 v = ((const float4*)in)[i];
  ((ushort4*)out)[i] = make_ushort4(f2bf(v.x), f2bf(v.y), f2bf(v.z), f2bf(v.w));
}

// ---------------- RMSNorm ----------------
__global__ void rmsnorm_kernel(const float* __restrict__ x, const float* __restrict__ w,
                               float* __restrict__ o32, u16* __restrict__ o16) {
  int row = blockIdx.x;
  int t = threadIdx.x;
  float4 v = ((const float4*)(x + (size_t)row * DD))[t];
  float ss = v.x * v.x + v.y * v.y + v.z * v.z + v.w * v.w;
  for (int o = 32; o > 0; o >>= 1) ss += __shfl_xor(ss, o);
  __shared__ float red[4];
  if ((t & 63) == 0) red[t >> 6] = ss;
  __syncthreads();
  float tot = red[0] + red[1] + red[2] + red[3];
  float r = rsqrtf(tot * (1.f / DD) + 1e-5f);
  float4 wv = ((const float4*)w)[t];
  float4 o;
  o.x = v.x * r * wv.x; o.y = v.y * r * wv.y; o.z = v.z * r * wv.z; o.w = v.w * r * wv.w;
  if (o32) ((float4*)(o32 + (size_t)row * DD))[t] = o;
  if (o16) ((ushort4*)(o16 + (size_t)row * DD))[t] =
      make_ushort4(f2bf(o.x), f2bf(o.y), f2bf(o.z), f2bf(o.w));
}

// ---------------- Plain MFMA GEMM (qkv, wo): C = A @ B^T (+addend) ----------------
__global__ __launch_bounds__(256) void gemm128(
    const u16* __restrict__ A, const u16* __restrict__ B,
    float* __restrict__ C, const float* __restrict__ addend, int N, int K) {
  __shared__ u16 As[128 * 32];
  __shared__ u16 Bs[128 * 32];
  int tid = threadIdx.x;
  int bm = blockIdx.x * 128;
  int bn = blockIdx.y * 128;
  const u16* Ag = A + (size_t)bm * K;
  const u16* Bg = B + (size_t)bn * K;
  int wave = tid >> 6, lane = tid & 63;
  int wm = wave >> 1, wn = wave & 1;
  int ml = lane & 15, quad = lane >> 4;

  floatx4 acc[4][4];
#pragma unroll
  for (int i = 0; i < 4; i++)
#pragma unroll
    for (int j = 0; j < 4; j++) acc[i][j] = (floatx4){0.f, 0.f, 0.f, 0.f};

  for (int k0 = 0; k0 < K; k0 += 32) {
#pragma unroll
    for (int r = 0; r < 2; r++) {
      int s = tid + r * 256;
      int row = s >> 2, kc = (s & 3) * 8;
      __builtin_amdgcn_global_load_lds(
          (const __attribute__((address_space(1))) unsigned*)(Ag + (size_t)row * K + k0 + kc),
          (__attribute__((address_space(3))) unsigned*)(As + s * 8), 16, 0, 0);
      __builtin_amdgcn_global_load_lds(
          (const __attribute__((address_space(1))) unsigned*)(Bg + (size_t)row * K + k0 + kc),
          (__attribute__((address_space(3))) unsigned*)(Bs + s * 8), 16, 0, 0);
    }
    __syncthreads();
    short8 a[4], b[4];
#pragma unroll
    for (int i = 0; i < 4; i++)
      a[i] = *(const short8*)(As + ((wm * 64 + i * 16 + ml) * 32 + quad * 8));
#pragma unroll
    for (int j = 0; j < 4; j++)
      b[j] = *(const short8*)(Bs + ((wn * 64 + j * 16 + ml) * 32 + quad * 8));
#pragma unroll
    for (int i = 0; i < 4; i++)
#pragma unroll
      for (int j = 0; j < 4; j++)
        acc[i][j] = __builtin_amdgcn_mfma_f32_16x16x32_bf16(a[i], b[j], acc[i][j], 0, 0, 0);
    __syncthreads();
  }
#pragma unroll
  for (int i = 0; i < 4; i++) {
#pragma unroll
    for (int j = 0; j < 4; j++) {
#pragma unroll
      for (int r = 0; r < 4; r++) {
        int row = bm + wm * 64 + i * 16 + quad * 4 + r;
        int col = bn + wn * 64 + j * 16 + ml;
        size_t idx = (size_t)row * N + col;
        float v = acc[i][j][r];
        if (addend) v += addend[idx];
        C[idx] = v;
      }
    }
  }
}

// ---------------- MoE stage 1 fused: x13 = silu(X@w1^T) * (X@w3^T), bf16 out ----------------
// Weights consumed DIRECTLY as fp32 (no separate convert kernel; cvt to bf16
// in regs during B staging). B reg-staged with XOR-swizzled LDS
// (byte ^= (row&6)<<3 -> conflict-free quarter-wave b128 reads). A staged via
// global_load_lds with PRE-SWIZZLED SOURCE chunk index (T21: LDS linear,
// source permuted), read with the same XOR.
__global__ __launch_bounds__(256, 3) void moe_stage1(
    const u16* __restrict__ xslot, const float* __restrict__ w1f, const float* __restrict__ w3f,
    const int* __restrict__ tmap, u16* __restrict__ x13) {
  __shared__ u16 As[128 * 32];
  __shared__ u16 B1s[64 * 32];
  __shared__ u16 B3s[64 * 32];
  int tI = blockIdx.y % NTILEMAX;
  int cI = blockIdx.x + 8 * (blockIdx.y / NTILEMAX);
  if (tI >= tmap[0]) return;
  int entry = tmap[1 + tI];
  int e = entry & 7;
  int row0 = (entry >> 3) * 128;
  int bn = cI * 64;
  const u16* Ag = xslot + (size_t)row0 * DD;
  const float* B1g = w1f + (size_t)e * NI * DD + (size_t)bn * DD;
  const float* B3g = w3f + (size_t)e * NI * DD + (size_t)bn * DD;
  int tid = threadIdx.x, wave = tid >> 6, lane = tid & 63;
  int wm = wave >> 1, wn = wave & 1;
  int ml = lane & 15, quad = lane >> 4;

  // B staging map: thread t -> row=t>>2, 8 contiguous floats at chunk bc8=t&3
  int brow = tid >> 2, bc8 = tid & 3;
  int wbyte = (brow * 64 + bc8 * 16) ^ ((brow & 6) << 3);
  const float* b1p = B1g + (size_t)brow * DD + bc8 * 8;
  const float* b3p = B3g + (size_t)brow * DD + bc8 * 8;

  floatx4 acc1[4][2], acc3[4][2];
#pragma unroll
  for (int i = 0; i < 4; i++)
#pragma unroll
    for (int j = 0; j < 2; j++) {
      acc1[i][j] = (floatx4){0.f, 0.f, 0.f, 0.f};
      acc3[i][j] = (floatx4){0.f, 0.f, 0.f, 0.f};
    }

  for (int k0 = 0; k0 < DD; k0 += 32) {
    // A: global_load_lds, source chunk pre-swizzled
#pragma unroll
    for (int r = 0; r < 2; r++) {
      int s = tid + r * 256;
      int row = s >> 2;
      int sc = (s & 3) ^ ((row >> 1) & 3);
      __builtin_amdgcn_global_load_lds(
          (const __attribute__((address_space(1))) unsigned*)(Ag + (size_t)row * DD + k0 + sc * 8),
          (__attribute__((address_space(3))) unsigned*)(As + s * 8), 16, 0, 0);
    }
    // B: fp32 global -> regs -> bf16 -> swizzled LDS write
    float4 u0 = *(const float4*)(b1p + k0);
    float4 u1 = *(const float4*)(b1p + k0 + 4);
    float4 v0 = *(const float4*)(b3p + k0);
    float4 v1 = *(const float4*)(b3p + k0 + 4);
    short8 pb1, pb3;
    pb1[0] = (short)f2bf(u0.x); pb1[1] = (short)f2bf(u0.y);
    pb1[2] = (short)f2bf(u0.z); pb1[3] = (short)f2bf(u0.w);
    pb1[4] = (short)f2bf(u1.x); pb1[5] = (short)f2bf(u1.y);
    pb1[6] = (short)f2bf(u1.z); pb1[7] = (short)f2bf(u1.w);
    pb3[0] = (short)f2bf(v0.x); pb3[1] = (short)f2bf(v0.y);
    pb3[2] = (short)f2bf(v0.z); pb3[3] = (short)f2bf(v0.w);
    pb3[4] = (short)f2bf(v1.x); pb3[5] = (short)f2bf(v1.y);
    pb3[6] = (short)f2bf(v1.z); pb3[7] = (short)f2bf(v1.w);
    *(short8*)((char*)B1s + wbyte) = pb1;
    *(short8*)((char*)B3s + wbyte) = pb3;
    __syncthreads();
    short8 a[4], b1[2], b3[2];
#pragma unroll
    for (int i = 0; i < 4; i++) {
      int row = wm * 64 + i * 16 + ml;
      int rb = (row * 64 + quad * 16) ^ ((row & 6) << 3);
      a[i] = *(const short8*)((const char*)As + rb);
    }
#pragma unroll
    for (int j = 0; j < 2; j++) {
      int rr = wn * 32 + j * 16 + ml;
      int rb = (rr * 64 + quad * 16) ^ ((rr & 6) << 3);
      b1[j] = *(const short8*)((const char*)B1s + rb);
      b3[j] = *(const short8*)((const char*)B3s + rb);
    }
#pragma unroll
    for (int i = 0; i < 4; i++)
#pragma unroll
      for (int j = 0; j < 2; j++) {
        acc1[i][j] = __builtin_amdgcn_mfma_f32_16x16x32_bf16(a[i], b1[j], acc1[i][j], 0, 0, 0);
        acc3[i][j] = __builtin_amdgcn_mfma_f32_16x16x32_bf16(a[i], b3[j], acc3[i][j], 0, 0, 0);
      }
    __syncthreads();
  }
#pragma unroll
  for (int i = 0; i < 4; i++) {
#pragma unroll
    for (int j = 0; j < 2; j++) {
#pragma unroll
      for (int r = 0; r < 4; r++) {
        int row = row0 + wm * 64 + i * 16 + quad * 4 + r;
        int col = bn + wn * 32 + j * 16 + ml;
        float v1 = acc1[i][j][r], v3 = acc3[i][j][r];
        float sil = v1 / (1.f + __expf(-v1));
        x13[(size_t)row * NI + col] = f2bf(sil * v3);
      }
    }
  }
}

// ---------------- MoE stage 2 split-K=2: pbuf[kh] = x13 @ w2^T (fp32 partials) ----------------
// 128x64 tile, w2 consumed directly as fp32 (reg-staged + swizzled LDS),
// A(x13) gload_lds with pre-swizzled source. Grid (8, 160):
// tI=y%40, g=x+8*(y/40) in [0,32): nt=g&15, kh=g>>4.
__global__ __launch_bounds__(256, 3) void moe_stage2(
    const u16* __restrict__ x13, const float* __restrict__ w2f,
    const int* __restrict__ tmap, float* __restrict__ pbuf) {
  __shared__ u16 As[128 * 32];
  __shared__ u16 Bs[64 * 32];
  int tI = blockIdx.y % NTILEMAX;
  int g = blockIdx.x + 8 * (blockIdx.y / NTILEMAX);
  int nt = g & 15, kh = g >> 4;
  if (tI >= tmap[0]) return;
  int entry = tmap[1 + tI];
  int e = entry & 7;
  int row0 = (entry >> 3) * 128;
  int bn = nt * 64;
  int kbeg = kh * (NI / 2), kend = kbeg + NI / 2;
  const u16* Ag = x13 + (size_t)row0 * NI;
  const float* Bg = w2f + (size_t)e * DD * NI + (size_t)bn * NI;
  float* Cp = pbuf + (size_t)kh * PCAP * DD;
  int tid = threadIdx.x, wave = tid >> 6, lane = tid & 63;
  int wm = wave >> 1, wn = wave & 1;
  int ml = lane & 15, quad = lane >> 4;

  int brow = tid >> 2, bc8 = tid & 3;
  int wbyte = (brow * 64 + bc8 * 16) ^ ((brow & 6) << 3);
  const float* bp = Bg + (size_t)brow * NI + bc8 * 8;

  floatx4 acc[4][2];
#pragma unroll
  for (int i = 0; i < 4; i++)
#pragma unroll
    for (int j = 0; j < 2; j++) acc[i][j] = (floatx4){0.f, 0.f, 0.f, 0.f};

  for (int k0 = kbeg; k0 < kend; k0 += 32) {
#pragma unroll
    for (int r = 0; r < 2; r++) {
      int s = tid + r * 256;
      int row = s >> 2;
      int sc = (s & 3) ^ ((row >> 1) & 3);
      __builtin_amdgcn_global_load_lds(
          (const __attribute__((address_space(1))) unsigned*)(Ag + (size_t)row * NI + k0 + sc * 8),
          (__attribute__((address_space(3))) unsigned*)(As + s * 8), 16, 0, 0);
    }
    float4 u0 = *(const float4*)(bp + k0);
    float4 u1 = *(const float4*)(bp + k0 + 4);
    short8 pb;
    pb[0] = (short)f2bf(u0.x); pb[1] = (short)f2bf(u0.y);
    pb[2] = (short)f2bf(u0.z); pb[3] = (short)f2bf(u0.w);
    pb[4] = (short)f2bf(u1.x); pb[5] = (short)f2bf(u1.y);
    pb[6] = (short)f2bf(u1.z); pb[7] = (short)f2bf(u1.w);
    *(short8*)((char*)Bs + wbyte) = pb;
    __syncthreads();
    short8 a[4], b[2];
#pragma unroll
    for (int i = 0; i < 4; i++) {
      int row = wm * 64 + i * 16 + ml;
      int rb = (row * 64 + quad * 16) ^ ((row & 6) << 3);
      a[i] = *(const short8*)((const char*)As + rb);
    }
#pragma unroll
    for (int j = 0; j < 2; j++) {
      int rr = wn * 32 + j * 16 + ml;
      int rb = (rr * 64 + quad * 16) ^ ((rr & 6) << 3);
      b[j] = *(const short8*)((const char*)Bs + rb);
    }
#pragma unroll
    for (int i = 0; i < 4; i++)
#pragma unroll
      for (int j = 0; j < 2; j++)
        acc[i][j] = __builtin_amdgcn_mfma_f32_16x16x32_bf16(a[i], b[j], acc[i][j], 0, 0, 0);
    __syncthreads();
  }
#pragma unroll
  for (int i = 0; i < 4; i++) {
#pragma unroll
    for (int j = 0; j < 2; j++) {
#pragma unroll
      for (int r = 0; r < 4; r++) {
        int row = row0 + wm * 64 + i * 16 + quad * 4 + r;
        int col = bn + wn * 32 + j * 16 + ml;
        Cp[(size_t)row * DD + col] = acc[i][j][r];
      }
    }
  }
}

// ---------------- RoPE: fp32 qkv -> bf16 qT [NH][S][64] (scaled 1/8), kT [NKVH][S][64] ----------------
__global__ void rope_kernel(const float* __restrict__ qkv, const float* __restrict__ freqs,
                            u16* __restrict__ qT, u16* __restrict__ kT) {
  int s = blockIdx.x;
  int tid = threadIdx.x;
#pragma unroll
  for (int r = 0; r < 2; r++) {
    int tt = r * 256 + tid;
    int hh = tt >> 5, i = tt & 31;
    const float* p = qkv + (size_t)s * QKVN + hh * 64 + 2 * i;
    float c = freqs[(s * 32 + i) * 2], sn = freqs[(s * 32 + i) * 2 + 1];
    float x0 = p[0], x1 = p[1];
    float r0 = (x0 * c - x1 * sn) * 0.125f;
    float r1 = (x1 * c + x0 * sn) * 0.125f;
    unsigned pk = (unsigned)f2bf(r0) | ((unsigned)f2bf(r1) << 16);
    *(unsigned*)(qT + ((size_t)hh * SS + s) * 64 + 2 * i) = pk;
  }
  if (tid < 128) {
    int hh = tid >> 5, i = tid & 31;
    const float* p = qkv + (size_t)s * QKVN + DD + hh * 64 + 2 * i;
    float c = freqs[(s * 32 + i) * 2], sn = freqs[(s * 32 + i) * 2 + 1];
    float x0 = p[0], x1 = p[1];
    float r0 = x0 * c - x1 * sn;
    float r1 = x1 * c + x0 * sn;
    unsigned pk = (unsigned)f2bf(r0) | ((unsigned)f2bf(r1) << 16);
    *(unsigned*)(kT + ((size_t)hh * SS + s) * 64 + 2 * i) = pk;
  }
}

// ---------------- V transpose: qkv v-part -> vT2 [NKVH*64][S] bf16 ----------------
__global__ void vtrans_kernel(const float* __restrict__ qkv, u16* __restrict__ vT2) {
  __shared__ u16 tile[64][65];
  int bs = blockIdx.x * 64;
  int bc = blockIdx.y * 64;
  int tid = threadIdx.x;
#pragma unroll
  for (int it = 0; it < 4; it++) {
    int idx = it * 256 + tid;
    int r = idx >> 4, c4 = idx & 15;
    float4 v = *(const float4*)(qkv + (size_t)(bs + r) * QKVN + DD + 256 + bc + c4 * 4);
    tile[r][c4 * 4 + 0] = f2bf(v.x);
    tile[r][c4 * 4 + 1] = f2bf(v.y);
    tile[r][c4 * 4 + 2] = f2bf(v.z);
    tile[r][c4 * 4 + 3] = f2bf(v.w);
  }
  __syncthreads();
#pragma unroll
  for (int it = 0; it < 4; it++) {
    int idx = it * 256 + tid;
    int cc = idx >> 4, s4 = idx & 15;
    ushort4 o = make_ushort4(tile[s4 * 4 + 0][cc], tile[s4 * 4 + 1][cc],
                             tile[s4 * 4 + 2][cc], tile[s4 * 4 + 3][cc]);
    *(ushort4*)(vT2 + (size_t)(bc + cc) * SS + bs + s4 * 4) = o;
  }
}

// ---------------- Flash attention: BQ=128 (4 waves x 32 rows), BKV=64, MFMA ----------------
#define BQ 128
#define BKV 64
__global__ __launch_bounds__(256) void attn_flash(const u16* __restrict__ qT,
                                                  const u16* __restrict__ kT,
                                                  const u16* __restrict__ vT2,
                                                  u16* __restrict__ y) {
  __shared__ u16 Ks[2 * 64 * 32];
  __shared__ u16 Vs[2 * 64 * 32];
  __shared__ u16 Ps[2 * 128 * 36];
  int t = blockIdx.x;
  int h = blockIdx.y;
  int kvh = h >> 2;
  int bq = t * BQ;
  int tid = threadIdx.x, wave = tid >> 6, lane = tid & 63;
  int ml = lane & 15, quad = lane >> 4;

  short8 qf[2][2];
#pragma unroll
  for (int i = 0; i < 2; i++)
#pragma unroll
    for (int c = 0; c < 2; c++)
      qf[i][c] = *(const short8*)(qT + ((size_t)h * SS + bq + wave * 32 + i * 16 + ml) * 64 +
                                  c * 32 + quad * 8);

  float m_i[2][4], l_i[2][4];
  floatx4 o_acc[2][4];
#pragma unroll
  for (int i = 0; i < 2; i++)
#pragma unroll
    for (int r = 0; r < 4; r++) {
      m_i[i][r] = -1e30f;
      l_i[i][r] = 0.f;
      o_acc[i][r] = (floatx4){0.f, 0.f, 0.f, 0.f};
    }

  int nkv = 2 * t + 2;
  for (int kt = 0; kt < nkv; kt++) {
    int bk = kt * BKV;
    __syncthreads();
#pragma unroll
    for (int r = 0; r < 2; r++) {
      int ch = r * 256 + tid;
      int c = ch >> 8, srow = (ch >> 2) & 63, o8 = ch & 3;
      __builtin_amdgcn_global_load_lds(
          (const __attribute__((address_space(1))) unsigned*)(
              kT + ((size_t)kvh * SS + bk + srow) * 64 + c * 32 + o8 * 8),
          (__attribute__((address_space(3))) unsigned*)(Ks + ch * 8), 16, 0, 0);
      __builtin_amdgcn_global_load_lds(
          (const __attribute__((address_space(1))) unsigned*)(
              vT2 + ((size_t)kvh * 64 + srow) * SS + bk + c * 32 + o8 * 8),
          (__attribute__((address_space(3))) unsigned*)(Vs + ch * 8), 16, 0, 0);
    }
    __syncthreads();

    floatx4 s_acc[2][4];
#pragma unroll
    for (int i = 0; i < 2; i++)
#pragma unroll
      for (int j = 0; j < 4; j++) s_acc[i][j] = (floatx4){0.f, 0.f, 0.f, 0.f};
#pragma unroll
    for (int c = 0; c < 2; c++) {
#pragma unroll
      for (int jk = 0; jk < 4; jk++) {
        short8 kf = *(const short8*)(Ks + c * 2048 + (jk * 16 + ml) * 32 + quad * 8);
#pragma unroll
        for (int i = 0; i < 2; i++)
          s_acc[i][jk] = __builtin_amdgcn_mfma_f32_16x16x32_bf16(qf[i][c], kf, s_acc[i][jk], 0, 0, 0);
      }
    }
    if (bk + BKV - 1 > bq) {
#pragma unroll
      for (int i = 0; i < 2; i++)
#pragma unroll
        for (int jk = 0; jk < 4; jk++)
#pragma unroll
          for (int r = 0; r < 4; r++) {
            int row = bq + wave * 32 + i * 16 + quad * 4 + r;
            int col = bk + jk * 16 + ml;
            if (col > row) s_acc[i][jk][r] = -1e30f;
          }
    }
#pragma unroll
    for (int i = 0; i < 2; i++) {
#pragma unroll
      for (int r = 0; r < 4; r++) {
        float mx = -1e30f;
#pragma unroll
        for (int jk = 0; jk < 4; jk++) mx = fmaxf(mx, s_acc[i][jk][r]);
        for (int o = 1; o < 16; o <<= 1) mx = fmaxf(mx, __shfl_xor(mx, o));
        float mnew = fmaxf(m_i[i][r], mx);
        float alpha = __expf(m_i[i][r] - mnew);
        m_i[i][r] = mnew;
        float rs = 0.f;
#pragma unroll
        for (int jk = 0; jk < 4; jk++) {
          float p = __expf(s_acc[i][jk][r] - mnew);
          s_acc[i][jk][r] = p;
          rs += p;
        }
        for (int o = 1; o < 16; o <<= 1) rs += __shfl_xor(rs, o);
        l_i[i][r] = l_i[i][r] * alpha + rs;
#pragma unroll
        for (int jd = 0; jd < 4; jd++) o_acc[i][jd][r] *= alpha;
      }
    }
#pragma unroll
    for (int i = 0; i < 2; i++)
#pragma unroll
      for (int jk = 0; jk < 4; jk++)
#pragma unroll
        for (int r = 0; r < 4; r++) {
          int row = wave * 32 + i * 16 + quad * 4 + r;
          int col = jk * 16 + ml;
          Ps[(col >> 5) * (128 * 36) + row * 36 + (col & 31)] = f2bf(s_acc[i][jk][r]);
        }
#pragma unroll
    for (int kc = 0; kc < 2; kc++) {
      short8 pf[2];
#pragma unroll
      for (int i = 0; i < 2; i++)
        pf[i] = *(const short8*)(Ps + kc * (128 * 36) + (wave * 32 + i * 16 + ml) * 36 + quad * 8);
#pragma unroll
      for (int jd = 0; jd < 4; jd++) {
        short8 vf = *(const short8*)(Vs + kc * 2048 + (jd * 16 + ml) * 32 + quad * 8);
#pragma unroll
        for (int i = 0; i < 2; i++)
          o_acc[i][jd] = __builtin_amdgcn_mfma_f32_16x16x32_bf16(pf[i], vf, o_acc[i][jd], 0, 0, 0);
      }
    }
  }
#pragma unroll
  for (int i = 0; i < 2; i++) {
    float inv[4];
#pragma unroll
    for (int r = 0; r < 4; r++) inv[r] = 1.f / l_i[i][r];
#pragma unroll
    for (int jd = 0; jd < 4; jd++)
#pragma unroll
      for (int r = 0; r < 4; r++) {
        int row = bq + wave * 32 + i * 16 + quad * 4 + r;
        int col = h * 64 + jd * 16 + ml;
        y[(size_t)row * DD + col] = f2bf(o_acc[i][jd][r] * inv[r]);
      }
  }
}

// ---------------- Gate ----------------
__global__ __launch_bounds__(64) void gate_kernel(const float* __restrict__ hf,
                                                  const float* __restrict__ gw,
                                                  int* __restrict__ ei, float* __restrict__ ew,
                                                  int* __restrict__ cnt) {
  int t = blockIdx.x;
  int lane = threadIdx.x;
  const float* xr = hf + (size_t)t * DD;
  float acc[NE] = {};
  for (int c = 0; c < DD / 64; c++) {
    float xv = xr[lane + 64 * c];
#pragma unroll
    for (int e = 0; e < NE; e++) acc[e] += xv * gw[e * DD + lane + 64 * c];
  }
#pragma unroll
  for (int e = 0; e < NE; e++)
    for (int o = 32; o > 0; o >>= 1) acc[e] += __shfl_xor(acc[e], o);
  if (lane == 0) {
    float mx = acc[0];
    for (int e = 1; e < NE; e++) mx = fmaxf(mx, acc[e]);
    float p[NE], sum = 0.f;
    for (int e = 0; e < NE; e++) { p[e] = __expf(acc[e] - mx); sum += p[e]; }
    for (int e = 0; e < NE; e++) p[e] /= sum;
    int i0 = 0;
    for (int e = 1; e < NE; e++) if (p[e] > p[i0]) i0 = e;
    int i1 = (i0 == 0) ? 1 : 0;
    for (int e = 0; e < NE; e++) if (e != i0 && p[e] > p[i1]) i1 = e;
    float w0 = p[i0], w1 = p[i1], s = w0 + w1;
    ei[t * 2] = i0; ei[t * 2 + 1] = i1;
    ew[t * 2] = w0 / s; ew[t * 2 + 1] = w1 / s;
    atomicAdd(&cnt[i0], 1);
    atomicAdd(&cnt[i1], 1);
  }
}

__global__ void zero_cnt_kernel(int* cnt) {
  if (threadIdx.x < NE) cnt[threadIdx.x] = 0;
}

__global__ void prefix_kernel(const int* __restrict__ cnt, int* __restrict__ poff,
                              int* __restrict__ fill) {
  if (threadIdx.x == 0) {
    int pacc = 0;
    for (int e = 0; e < NE; e++) {
      poff[e] = pacc;
      pacc += (cnt[e] + 127) & ~127;
    }
    poff[NE] = pacc;
  }
  if (threadIdx.x < NE) fill[threadIdx.x] = 0;
}

// tmap[0] = ntiles, tmap[1+i] = (rowoff128 << 3) | expert
__global__ void tilemap_kernel(const int* __restrict__ poff, int* __restrict__ tmap) {
  if (threadIdx.x == 0) {
    int n = 0;
    for (int e = 0; e < NE; e++) {
      int r0 = poff[e] >> 7, r1 = poff[e + 1] >> 7;
      for (int r = r0; r < r1; r++) tmap[1 + n++] = (r << 3) | e;
    }
    tmap[0] = n;
  }
}

__global__ void fill_kernel(const int* __restrict__ ei, const int* __restrict__ poff,
                            int* __restrict__ fill, int* __restrict__ slot_of) {
  int t = blockIdx.x * blockDim.x + threadIdx.x;
  if (t >= SS) return;
  for (int a = 0; a < 2; a++) {
    int e = ei[t * 2 + a];
    int pos = atomicAdd(&fill[e], 1);
    slot_of[t * 2 + a] = poff[e] + pos;
  }
}

__global__ void gather_kernel(const u16* __restrict__ hf16, const int* __restrict__ slot_of,
                              u16* __restrict__ xslot) {
  int t = blockIdx.x;
  uint2 v = ((const uint2*)(hf16 + (size_t)t * DD))[threadIdx.x];
  for (int a = 0; a < 2; a++) {
    int slot = slot_of[t * 2 + a];
    ((uint2*)(xslot + (size_t)slot * DD))[threadIdx.x] = v;
  }
}

// out = h + w0*(p0[s0]+p1[s0]) + w1*(p0[s1]+p1[s1])
__global__ void final_kernel(const float* __restrict__ h, const float* __restrict__ p0,
                             const float* __restrict__ p1, const int* __restrict__ slot_of,
                             const float* __restrict__ ew, float* __restrict__ out) {
  int t = blockIdx.x;
  int s0 = slot_of[t * 2], s1 = slot_of[t * 2 + 1];
  float w0 = ew[t * 2], w1 = ew[t * 2 + 1];
  float4 hv = ((const float4*)(h + (size_t)t * DD))[threadIdx.x];
  float4 a0 = ((const float4*)(p0 + (size_t)s0 * DD))[threadIdx.x];
  float4 a1 = ((const float4*)(p1 + (size_t)s0 * DD))[threadIdx.x];
  float4 b0 = ((const float4*)(p0 + (size_t)s1 * DD))[threadIdx.x];
  float4 b1 = ((const float4*)(p1 + (size_t)s1 * DD))[threadIdx.x];
  float4 o;
  o.x = hv.x + w0 * (a0.x + a1.x) + w1 * (b0.x + b1.x);
  o.y = hv.y + w0 * (a0.y + a1.y) + w1 * (b0.y + b1.y);
  o.z = hv.z + w0 * (a0.z + a1.z) + w1 * (b0.z + b1.z);
  o.w = hv.w + w0 * (a0.w + a1.w) + w1 * (b0.w + b1.w);
  ((float4*)(out + (size_t)t * DD))[threadIdx.x] = o;
}

extern "C" void kernel_launch(void* const* d_in, const int* in_sizes, int n_in,
                              void* d_out, int out_size, void* d_ws, size_t ws_size,
                              hipStream_t stream) {
  const float* x = (const float*)d_in[0];
  const float* wqkv = (const float*)d_in[1];
  const float* wo = (const float*)d_in[2];
  const float* gate_w = (const float*)d_in[3];
  const float* w1 = (const float*)d_in[4];
  const float* w2 = (const float*)d_in[5];
  const float* w3 = (const float*)d_in[6];
  const float* attn_norm_w = (const float*)d_in[7];
  const float* ffn_norm_w = (const float*)d_in[8];
  const float* freqs = (const float*)d_in[9];
  float* out = (float*)d_out;

  char* ws = (char*)d_ws;
  size_t off = 0;
  auto alloc = [&](size_t bytes) -> char* {
    char* p = ws + off;
    off = (off + bytes + 255) & ~(size_t)255;
    return p;
  };
  u16* hn16    = (u16*)alloc((size_t)SS * DD * 2);   // aliased as qT after qkv GEMM
  float* qkv   = (float*)alloc((size_t)SS * QKVN * 4);
  u16* y16     = (u16*)alloc((size_t)SS * DD * 2);
  float* hbuf  = (float*)alloc((size_t)SS * DD * 4);
  float* hf    = (float*)alloc((size_t)SS * DD * 4);
  u16* hf16    = (u16*)alloc((size_t)SS * DD * 2);
  u16* kT      = (u16*)alloc((size_t)NKVH * SS * HDIM * 2);
  u16* vT2     = (u16*)alloc((size_t)NKVH * HDIM * SS * 2);
  u16* wqkv16  = (u16*)alloc((size_t)QKVN * DD * 2);
  u16* wo16    = (u16*)alloc((size_t)DD * DD * 2);
  u16* xslot   = (u16*)alloc((size_t)PCAP * DD * 2);
  u16* x13     = (u16*)alloc((size_t)PCAP * NI * 2);
  float* pbuf  = (float*)alloc((size_t)2 * PCAP * DD * 4);
  int* ei      = (int*)alloc((size_t)SS * 2 * 4);
  float* ew    = (float*)alloc((size_t)SS * 2 * 4);
  int* slot_of = (int*)alloc((size_t)SS * 2 * 4);
  int* cnt     = (int*)alloc(NE * 4);
  int* poff    = (int*)alloc((NE + 1) * 4);
  int* fill    = (int*)alloc(NE * 4);
  int* tmap    = (int*)alloc((NTILEMAX + 1) * 4);
  u16* qT      = hn16;

  auto conv = [&](const float* src, u16* dst, size_t n) {
    int n4 = (int)(n / 4);
    f32_to_bf16_kernel<<<(n4 + 255) / 256, 256, 0, stream>>>(src, dst, n4);
  };

  zero_cnt_kernel<<<1, 64, 0, stream>>>(cnt);
  conv(wqkv, wqkv16, (size_t)QKVN * DD);
  conv(wo, wo16, (size_t)DD * DD);
  // w1/w3/w2: consumed directly as fp32 by moe_stage1/2 (no bulk convert)

  // ---- attention path ----
  rmsnorm_kernel<<<SS, 256, 0, stream>>>(x, attn_norm_w, nullptr, hn16);
  gemm128<<<dim3(SS / 128, QKVN / 128), 256, 0, stream>>>(hn16, wqkv16, qkv, nullptr, QKVN, DD);
  rope_kernel<<<SS, 256, 0, stream>>>(qkv, freqs, qT, kT);
  vtrans_kernel<<<dim3(SS / 64, 4), 256, 0, stream>>>(qkv, vT2);
  attn_flash<<<dim3(SS / BQ, NH), 256, 0, stream>>>(qT, kT, vT2, y16);
  gemm128<<<dim3(SS / 128, DD / 128), 256, 0, stream>>>(y16, wo16, hbuf, x, DD, DD);

  // ---- MoE path ----
  rmsnorm_kernel<<<SS, 256, 0, stream>>>(hbuf, ffn_norm_w, hf, hf16);
  gate_kernel<<<SS, 64, 0, stream>>>(hf, gate_w, ei, ew, cnt);
  prefix_kernel<<<1, 64, 0, stream>>>(cnt, poff, fill);
  tilemap_kernel<<<1, 64, 0, stream>>>(poff, tmap);
  fill_kernel<<<(SS + 255) / 256, 256, 0, stream>>>(ei, poff, fill, slot_of);
  gather_kernel<<<SS, 256, 0, stream>>>(hf16, slot_of, xslot);
  // XCD-affinity grids: stage1 (8, 7*40), stage2 (8, 4*40)
  moe_stage1<<<dim3(8, (NI / 64 / 8) * NTILEMAX), 256, 0, stream>>>(xslot, w1, w3, tmap, x13);
  moe_stage2<<<dim3(8, 4 * NTILEMAX), 256, 0, stream>>>(x13, w2, tmap, pbuf);
  final_kernel<<<SS, 256, 0, stream>>>(hbuf, pbuf, pbuf + (size_t)PCAP * DD, slot_of, ew, out);
}

// Round 5
// 739.337 us; speedup vs baseline: 1.2003x; 1.0309x over previous
//
#include <hip/hip_runtime.h>
#include <hip/hip_bf16.h>
#include <math.h>

#define SS 2048
#define DD 1024
#define NH 16
#define NKVH 4
#define HDIM 64
#define NE 8
#define NI 3584
#define QKVN 1536
#define PCAP 5120
#define NTILEMAX 40   // PCAP/128

typedef unsigned short u16;
typedef short short8 __attribute__((ext_vector_type(8)));
typedef float floatx4 __attribute__((ext_vector_type(4)));

__device__ inline u16 f2bf(float f) {
  unsigned u = __float_as_uint(f);
  unsigned r = u + 0x7fffu + ((u >> 16) & 1u);
  return (u16)(r >> 16);
}
__device__ inline float bf2f(u16 h) { return __uint_as_float((unsigned)h << 16); }

// ---------------- fp32 -> bf16 bulk convert ----------------
__global__ void f32_to_bf16_kernel(const float* __restrict__ in, u16* __restrict__ out, int n4) {
  int i = blockIdx.x * 256 + threadIdx.x;
  if (i >= n4) return;
  float4 v = ((const float4*)in)[i];
  ((ushort4*)out)[i] = make_ushort4(f2bf(v.x), f2bf(v.y), f2bf(v.z), f2bf(v.w));
}

// ---------------- RMSNorm ----------------
__global__ void rmsnorm_kernel(const float* __restrict__ x, const float* __restrict__ w,
                               float* __restrict__ o32, u16* __restrict__ o16) {
  int row = blockIdx.x;
  int t = threadIdx.x;
  float4 v = ((const float4*)(x + (size_t)row * DD))[t];
  float ss = v.x * v.x + v.y * v.y + v.z * v.z + v.w * v.w;
  for (int o = 32; o > 0; o >>= 1) ss += __shfl_xor(ss, o);
  __shared__ float red[4];
  if ((t & 63) == 0) red[t >> 6] = ss;
  __syncthreads();
  float tot = red[0] + red[1] + red[2] + red[3];
  float r = rsqrtf(tot * (1.f / DD) + 1e-5f);
  float4 wv = ((const float4*)w)[t];
  float4 o;
  o.x = v.x * r * wv.x; o.y = v.y * r * wv.y; o.z = v.z * r * wv.z; o.w = v.w * r * wv.w;
  if (o32) ((float4*)(o32 + (size_t)row * DD))[t] = o;
  if (o16) ((ushort4*)(o16 + (size_t)row * DD))[t] =
      make_ushort4(f2bf(o.x), f2bf(o.y), f2bf(o.z), f2bf(o.w));
}

// ---------------- Plain MFMA GEMM (qkv, wo): C = A @ B^T (+addend) ----------------
__global__ __launch_bounds__(256) void gemm128(
    const u16* __restrict__ A, const u16* __restrict__ B,
    float* __restrict__ C, const float* __restrict__ addend, int N, int K) {
  __shared__ u16 As[128 * 32];
  __shared__ u16 Bs[128 * 32];
  int tid = threadIdx.x;
  int bm = blockIdx.x * 128;
  int bn = blockIdx.y * 128;
  const u16* Ag = A + (size_t)bm * K;
  const u16* Bg = B + (size_t)bn * K;
  int wave = tid >> 6, lane = tid & 63;
  int wm = wave >> 1, wn = wave & 1;
  int ml = lane & 15, quad = lane >> 4;

  floatx4 acc[4][4];
#pragma unroll
  for (int i = 0; i < 4; i++)
#pragma unroll
    for (int j = 0; j < 4; j++) acc[i][j] = (floatx4){0.f, 0.f, 0.f, 0.f};

  for (int k0 = 0; k0 < K; k0 += 32) {
#pragma unroll
    for (int r = 0; r < 2; r++) {
      int s = tid + r * 256;
      int row = s >> 2, kc = (s & 3) * 8;
      __builtin_amdgcn_global_load_lds(
          (const __attribute__((address_space(1))) unsigned*)(Ag + (size_t)row * K + k0 + kc),
          (__attribute__((address_space(3))) unsigned*)(As + s * 8), 16, 0, 0);
      __builtin_amdgcn_global_load_lds(
          (const __attribute__((address_space(1))) unsigned*)(Bg + (size_t)row * K + k0 + kc),
          (__attribute__((address_space(3))) unsigned*)(Bs + s * 8), 16, 0, 0);
    }
    __syncthreads();
    short8 a[4], b[4];
#pragma unroll
    for (int i = 0; i < 4; i++)
      a[i] = *(const short8*)(As + ((wm * 64 + i * 16 + ml) * 32 + quad * 8));
#pragma unroll
    for (int j = 0; j < 4; j++)
      b[j] = *(const short8*)(Bs + ((wn * 64 + j * 16 + ml) * 32 + quad * 8));
#pragma unroll
    for (int i = 0; i < 4; i++)
#pragma unroll
      for (int j = 0; j < 4; j++)
        acc[i][j] = __builtin_amdgcn_mfma_f32_16x16x32_bf16(a[i], b[j], acc[i][j], 0, 0, 0);
    __syncthreads();
  }
#pragma unroll
  for (int i = 0; i < 4; i++) {
#pragma unroll
    for (int j = 0; j < 4; j++) {
#pragma unroll
      for (int r = 0; r < 4; r++) {
        int row = bm + wm * 64 + i * 16 + quad * 4 + r;
        int col = bn + wn * 64 + j * 16 + ml;
        size_t idx = (size_t)row * N + col;
        float v = acc[i][j][r];
        if (addend) v += addend[idx];
        C[idx] = v;
      }
    }
  }
}

// ---------------- MoE stage 1 fused: x13 = silu(X@w1^T) * (X@w3^T), bf16 out ----------------
// Round 5: 2-phase double-buffered pipeline. Per iter: issue B(k+1) global
// loads (oldest in vmcnt queue), A(k+1) gload_lds into other buffer, then
// ds_read+MFMA on k, then cvt+ds_write B(k+1) (compiler waits vmcnt(2), A
// stays in flight), one barrier. HBM latency hides under the compute phase.
// fp32 weights consumed directly; XOR-swizzled LDS (conflicts = 0 in r4).
__global__ __launch_bounds__(256, 3) void moe_stage1(
    const u16* __restrict__ xslot, const float* __restrict__ w1f, const float* __restrict__ w3f,
    const int* __restrict__ tmap, u16* __restrict__ x13) {
  __shared__ u16 As[2][128 * 32];
  __shared__ u16 B1s[2][64 * 32];
  __shared__ u16 B3s[2][64 * 32];
  int tI = blockIdx.y % NTILEMAX;
  int cI = blockIdx.x + 8 * (blockIdx.y / NTILEMAX);
  if (tI >= tmap[0]) return;
  int entry = tmap[1 + tI];
  int e = entry & 7;
  int row0 = (entry >> 3) * 128;
  int bn = cI * 64;
  const u16* Ag = xslot + (size_t)row0 * DD;
  const float* B1g = w1f + (size_t)e * NI * DD + (size_t)bn * DD;
  const float* B3g = w3f + (size_t)e * NI * DD + (size_t)bn * DD;
  int tid = threadIdx.x, wave = tid >> 6, lane = tid & 63;
  int wm = wave >> 1, wn = wave & 1;
  int ml = lane & 15, quad = lane >> 4;

  int brow = tid >> 2, bc8 = tid & 3;
  int wbyte = (brow * 64 + bc8 * 16) ^ ((brow & 6) << 3);
  const float* b1p = B1g + (size_t)brow * DD + bc8 * 8;
  const float* b3p = B3g + (size_t)brow * DD + bc8 * 8;

  // A staging maps (2 chunks/thread), source chunk pre-swizzled
  int s0_ = tid, arow0 = s0_ >> 2, asc0 = (s0_ & 3) ^ ((arow0 >> 1) & 3);
  int s1_ = tid + 256, arow1 = s1_ >> 2, asc1 = (s1_ & 3) ^ ((arow1 >> 1) & 3);

  floatx4 acc1[4][2], acc3[4][2];
#pragma unroll
  for (int i = 0; i < 4; i++)
#pragma unroll
    for (int j = 0; j < 2; j++) {
      acc1[i][j] = (floatx4){0.f, 0.f, 0.f, 0.f};
      acc3[i][j] = (floatx4){0.f, 0.f, 0.f, 0.f};
    }

  // ---- prologue: stage k=0 into buf 0 ----
  {
    float4 u0 = *(const float4*)(b1p + 0);
    float4 u1 = *(const float4*)(b1p + 4);
    float4 v0 = *(const float4*)(b3p + 0);
    float4 v1 = *(const float4*)(b3p + 4);
    __builtin_amdgcn_global_load_lds(
        (const __attribute__((address_space(1))) unsigned*)(Ag + (size_t)arow0 * DD + 0 + asc0 * 8),
        (__attribute__((address_space(3))) unsigned*)(As[0] + s0_ * 8), 16, 0, 0);
    __builtin_amdgcn_global_load_lds(
        (const __attribute__((address_space(1))) unsigned*)(Ag + (size_t)arow1 * DD + 0 + asc1 * 8),
        (__attribute__((address_space(3))) unsigned*)(As[0] + s1_ * 8), 16, 0, 0);
    short8 pb1, pb3;
    pb1[0] = (short)f2bf(u0.x); pb1[1] = (short)f2bf(u0.y);
    pb1[2] = (short)f2bf(u0.z); pb1[3] = (short)f2bf(u0.w);
    pb1[4] = (short)f2bf(u1.x); pb1[5] = (short)f2bf(u1.y);
    pb1[6] = (short)f2bf(u1.z); pb1[7] = (short)f2bf(u1.w);
    pb3[0] = (short)f2bf(v0.x); pb3[1] = (short)f2bf(v0.y);
    pb3[2] = (short)f2bf(v0.z); pb3[3] = (short)f2bf(v0.w);
    pb3[4] = (short)f2bf(v1.x); pb3[5] = (short)f2bf(v1.y);
    pb3[6] = (short)f2bf(v1.z); pb3[7] = (short)f2bf(v1.w);
    *(short8*)((char*)B1s[0] + wbyte) = pb1;
    *(short8*)((char*)B3s[0] + wbyte) = pb3;
  }
  __syncthreads();

  for (int k = 0; k < DD / 32; k++) {
    int cur = k & 1, nxt = cur ^ 1;
    int kn = (k + 1) * 32;
    bool pf = (k + 1 < DD / 32);
    float4 u0, u1, v0, v1;
    if (pf) {
      // B(k+1) loads first (oldest in queue), then A(k+1) gload_lds
      u0 = *(const float4*)(b1p + kn);
      u1 = *(const float4*)(b1p + kn + 4);
      v0 = *(const float4*)(b3p + kn);
      v1 = *(const float4*)(b3p + kn + 4);
      __builtin_amdgcn_global_load_lds(
          (const __attribute__((address_space(1))) unsigned*)(Ag + (size_t)arow0 * DD + kn + asc0 * 8),
          (__attribute__((address_space(3))) unsigned*)(As[nxt] + s0_ * 8), 16, 0, 0);
      __builtin_amdgcn_global_load_lds(
          (const __attribute__((address_space(1))) unsigned*)(Ag + (size_t)arow1 * DD + kn + asc1 * 8),
          (__attribute__((address_space(3))) unsigned*)(As[nxt] + s1_ * 8), 16, 0, 0);
    }
    short8 a[4], b1[2], b3[2];
#pragma unroll
    for (int i = 0; i < 4; i++) {
      int row = wm * 64 + i * 16 + ml;
      int rb = (row * 64 + quad * 16) ^ ((row & 6) << 3);
      a[i] = *(const short8*)((const char*)As[cur] + rb);
    }
#pragma unroll
    for (int j = 0; j < 2; j++) {
      int rr = wn * 32 + j * 16 + ml;
      int rb = (rr * 64 + quad * 16) ^ ((rr & 6) << 3);
      b1[j] = *(const short8*)((const char*)B1s[cur] + rb);
      b3[j] = *(const short8*)((const char*)B3s[cur] + rb);
    }
#pragma unroll
    for (int i = 0; i < 4; i++)
#pragma unroll
      for (int j = 0; j < 2; j++) {
        acc1[i][j] = __builtin_amdgcn_mfma_f32_16x16x32_bf16(a[i], b1[j], acc1[i][j], 0, 0, 0);
        acc3[i][j] = __builtin_amdgcn_mfma_f32_16x16x32_bf16(a[i], b3[j], acc3[i][j], 0, 0, 0);
      }
    if (pf) {
      short8 pb1, pb3;
      pb1[0] = (short)f2bf(u0.x); pb1[1] = (short)f2bf(u0.y);
      pb1[2] = (short)f2bf(u0.z); pb1[3] = (short)f2bf(u0.w);
      pb1[4] = (short)f2bf(u1.x); pb1[5] = (short)f2bf(u1.y);
      pb1[6] = (short)f2bf(u1.z); pb1[7] = (short)f2bf(u1.w);
      pb3[0] = (short)f2bf(v0.x); pb3[1] = (short)f2bf(v0.y);
      pb3[2] = (short)f2bf(v0.z); pb3[3] = (short)f2bf(v0.w);
      pb3[4] = (short)f2bf(v1.x); pb3[5] = (short)f2bf(v1.y);
      pb3[6] = (short)f2bf(v1.z); pb3[7] = (short)f2bf(v1.w);
      *(short8*)((char*)B1s[nxt] + wbyte) = pb1;
      *(short8*)((char*)B3s[nxt] + wbyte) = pb3;
    }
    __syncthreads();
  }
#pragma unroll
  for (int i = 0; i < 4; i++) {
#pragma unroll
    for (int j = 0; j < 2; j++) {
#pragma unroll
      for (int r = 0; r < 4; r++) {
        int row = row0 + wm * 64 + i * 16 + quad * 4 + r;
        int col = bn + wn * 32 + j * 16 + ml;
        float v1 = acc1[i][j][r], v3 = acc3[i][j][r];
        float sil = v1 / (1.f + __expf(-v1));
        x13[(size_t)row * NI + col] = f2bf(sil * v3);
      }
    }
  }
}

// ---------------- MoE stage 2 split-K=2: pbuf[kh] = x13 @ w2^T (fp32 partials) ----------------
// Round 5: same 2-phase double-buffered pipeline. 128x64 tile, fp32 w2.
__global__ __launch_bounds__(256, 3) void moe_stage2(
    const u16* __restrict__ x13, const float* __restrict__ w2f,
    const int* __restrict__ tmap, float* __restrict__ pbuf) {
  __shared__ u16 As[2][128 * 32];
  __shared__ u16 Bs[2][64 * 32];
  int tI = blockIdx.y % NTILEMAX;
  int g = blockIdx.x + 8 * (blockIdx.y / NTILEMAX);
  int nt = g & 15, kh = g >> 4;
  if (tI >= tmap[0]) return;
  int entry = tmap[1 + tI];
  int e = entry & 7;
  int row0 = (entry >> 3) * 128;
  int bn = nt * 64;
  int kbeg = kh * (NI / 2);
  const u16* Ag = x13 + (size_t)row0 * NI;
  const float* Bg = w2f + (size_t)e * DD * NI + (size_t)bn * NI;
  float* Cp = pbuf + (size_t)kh * PCAP * DD;
  int tid = threadIdx.x, wave = tid >> 6, lane = tid & 63;
  int wm = wave >> 1, wn = wave & 1;
  int ml = lane & 15, quad = lane >> 4;

  int brow = tid >> 2, bc8 = tid & 3;
  int wbyte = (brow * 64 + bc8 * 16) ^ ((brow & 6) << 3);
  const float* bp = Bg + (size_t)brow * NI + bc8 * 8;

  int s0_ = tid, arow0 = s0_ >> 2, asc0 = (s0_ & 3) ^ ((arow0 >> 1) & 3);
  int s1_ = tid + 256, arow1 = s1_ >> 2, asc1 = (s1_ & 3) ^ ((arow1 >> 1) & 3);

  floatx4 acc[4][2];
#pragma unroll
  for (int i = 0; i < 4; i++)
#pragma unroll
    for (int j = 0; j < 2; j++) acc[i][j] = (floatx4){0.f, 0.f, 0.f, 0.f};

  // ---- prologue: stage kk=0 into buf 0 ----
  {
    float4 u0 = *(const float4*)(bp + kbeg);
    float4 u1 = *(const float4*)(bp + kbeg + 4);
    __builtin_amdgcn_global_load_lds(
        (const __attribute__((address_space(1))) unsigned*)(Ag + (size_t)arow0 * NI + kbeg + asc0 * 8),
        (__attribute__((address_space(3))) unsigned*)(As[0] + s0_ * 8), 16, 0, 0);
    __builtin_amdgcn_global_load_lds(
        (const __attribute__((address_space(1))) unsigned*)(Ag + (size_t)arow1 * NI + kbeg + asc1 * 8),
        (__attribute__((address_space(3))) unsigned*)(As[0] + s1_ * 8), 16, 0, 0);
    short8 pb;
    pb[0] = (short)f2bf(u0.x); pb[1] = (short)f2bf(u0.y);
    pb[2] = (short)f2bf(u0.z); pb[3] = (short)f2bf(u0.w);
    pb[4] = (short)f2bf(u1.x); pb[5] = (short)f2bf(u1.y);
    pb[6] = (short)f2bf(u1.z); pb[7] = (short)f2bf(u1.w);
    *(short8*)((char*)Bs[0] + wbyte) = pb;
  }
  __syncthreads();

  const int NK = (NI / 2) / 32;  // 56
  for (int kk = 0; kk < NK; kk++) {
    int cur = kk & 1, nxt = cur ^ 1;
    int kn = kbeg + (kk + 1) * 32;
    bool pf = (kk + 1 < NK);
    float4 u0, u1;
    if (pf) {
      u0 = *(const float4*)(bp + kn);
      u1 = *(const float4*)(bp + kn + 4);
      __builtin_amdgcn_global_load_lds(
          (const __attribute__((address_space(1))) unsigned*)(Ag + (size_t)arow0 * NI + kn + asc0 * 8),
          (__attribute__((address_space(3))) unsigned*)(As[nxt] + s0_ * 8), 16, 0, 0);
      __builtin_amdgcn_global_load_lds(
          (const __attribute__((address_space(1))) unsigned*)(Ag + (size_t)arow1 * NI + kn + asc1 * 8),
          (__attribute__((address_space(3))) unsigned*)(As[nxt] + s1_ * 8), 16, 0, 0);
    }
    short8 a[4], b[2];
#pragma unroll
    for (int i = 0; i < 4; i++) {
      int row = wm * 64 + i * 16 + ml;
      int rb = (row * 64 + quad * 16) ^ ((row & 6) << 3);
      a[i] = *(const short8*)((const char*)As[cur] + rb);
    }
#pragma unroll
    for (int j = 0; j < 2; j++) {
      int rr = wn * 32 + j * 16 + ml;
      int rb = (rr * 64 + quad * 16) ^ ((rr & 6) << 3);
      b[j] = *(const short8*)((const char*)Bs[cur] + rb);
    }
#pragma unroll
    for (int i = 0; i < 4; i++)
#pragma unroll
      for (int j = 0; j < 2; j++)
        acc[i][j] = __builtin_amdgcn_mfma_f32_16x16x32_bf16(a[i], b[j], acc[i][j], 0, 0, 0);
    if (pf) {
      short8 pb;
      pb[0] = (short)f2bf(u0.x); pb[1] = (short)f2bf(u0.y);
      pb[2] = (short)f2bf(u0.z); pb[3] = (short)f2bf(u0.w);
      pb[4] = (short)f2bf(u1.x); pb[5] = (short)f2bf(u1.y);
      pb[6] = (short)f2bf(u1.z); pb[7] = (short)f2bf(u1.w);
      *(short8*)((char*)Bs[nxt] + wbyte) = pb;
    }
    __syncthreads();
  }
#pragma unroll
  for (int i = 0; i < 4; i++) {
#pragma unroll
    for (int j = 0; j < 2; j++) {
#pragma unroll
      for (int r = 0; r < 4; r++) {
        int row = row0 + wm * 64 + i * 16 + quad * 4 + r;
        int col = bn + wn * 32 + j * 16 + ml;
        Cp[(size_t)row * DD + col] = acc[i][j][r];
      }
    }
  }
}

// ---------------- RoPE: fp32 qkv -> bf16 qT [NH][S][64] (scaled 1/8), kT [NKVH][S][64] ----------------
__global__ void rope_kernel(const float* __restrict__ qkv, const float* __restrict__ freqs,
                            u16* __restrict__ qT, u16* __restrict__ kT) {
  int s = blockIdx.x;
  int tid = threadIdx.x;
#pragma unroll
  for (int r = 0; r < 2; r++) {
    int tt = r * 256 + tid;
    int hh = tt >> 5, i = tt & 31;
    const float* p = qkv + (size_t)s * QKVN + hh * 64 + 2 * i;
    float c = freqs[(s * 32 + i) * 2], sn = freqs[(s * 32 + i) * 2 + 1];
    float x0 = p[0], x1 = p[1];
    float r0 = (x0 * c - x1 * sn) * 0.125f;
    float r1 = (x1 * c + x0 * sn) * 0.125f;
    unsigned pk = (unsigned)f2bf(r0) | ((unsigned)f2bf(r1) << 16);
    *(unsigned*)(qT + ((size_t)hh * SS + s) * 64 + 2 * i) = pk;
  }
  if (tid < 128) {
    int hh = tid >> 5, i = tid & 31;
    const float* p = qkv + (size_t)s * QKVN + DD + hh * 64 + 2 * i;
    float c = freqs[(s * 32 + i) * 2], sn = freqs[(s * 32 + i) * 2 + 1];
    float x0 = p[0], x1 = p[1];
    float r0 = x0 * c - x1 * sn;
    float r1 = x1 * c + x0 * sn;
    unsigned pk = (unsigned)f2bf(r0) | ((unsigned)f2bf(r1) << 16);
    *(unsigned*)(kT + ((size_t)hh * SS + s) * 64 + 2 * i) = pk;
  }
}

// ---------------- V transpose: qkv v-part -> vT2 [NKVH*64][S] bf16 ----------------
__global__ void vtrans_kernel(const float* __restrict__ qkv, u16* __restrict__ vT2) {
  __shared__ u16 tile[64][65];
  int bs = blockIdx.x * 64;
  int bc = blockIdx.y * 64;
  int tid = threadIdx.x;
#pragma unroll
  for (int it = 0; it < 4; it++) {
    int idx = it * 256 + tid;
    int r = idx >> 4, c4 = idx & 15;
    float4 v = *(const float4*)(qkv + (size_t)(bs + r) * QKVN + DD + 256 + bc + c4 * 4);
    tile[r][c4 * 4 + 0] = f2bf(v.x);
    tile[r][c4 * 4 + 1] = f2bf(v.y);
    tile[r][c4 * 4 + 2] = f2bf(v.z);
    tile[r][c4 * 4 + 3] = f2bf(v.w);
  }
  __syncthreads();
#pragma unroll
  for (int it = 0; it < 4; it++) {
    int idx = it * 256 + tid;
    int cc = idx >> 4, s4 = idx & 15;
    ushort4 o = make_ushort4(tile[s4 * 4 + 0][cc], tile[s4 * 4 + 1][cc],
                             tile[s4 * 4 + 2][cc], tile[s4 * 4 + 3][cc]);
    *(ushort4*)(vT2 + (size_t)(bc + cc) * SS + bs + s4 * 4) = o;
  }
}

// ---------------- Flash attention: BQ=128 (4 waves x 32 rows), BKV=64, MFMA ----------------
#define BQ 128
#define BKV 64
__global__ __launch_bounds__(256) void attn_flash(const u16* __restrict__ qT,
                                                  const u16* __restrict__ kT,
                                                  const u16* __restrict__ vT2,
                                                  u16* __restrict__ y) {
  __shared__ u16 Ks[2 * 64 * 32];
  __shared__ u16 Vs[2 * 64 * 32];
  __shared__ u16 Ps[2 * 128 * 36];
  int t = blockIdx.x;
  int h = blockIdx.y;
  int kvh = h >> 2;
  int bq = t * BQ;
  int tid = threadIdx.x, wave = tid >> 6, lane = tid & 63;
  int ml = lane & 15, quad = lane >> 4;

  short8 qf[2][2];
#pragma unroll
  for (int i = 0; i < 2; i++)
#pragma unroll
    for (int c = 0; c < 2; c++)
      qf[i][c] = *(const short8*)(qT + ((size_t)h * SS + bq + wave * 32 + i * 16 + ml) * 64 +
                                  c * 32 + quad * 8);

  float m_i[2][4], l_i[2][4];
  floatx4 o_acc[2][4];
#pragma unroll
  for (int i = 0; i < 2; i++)
#pragma unroll
    for (int r = 0; r < 4; r++) {
      m_i[i][r] = -1e30f;
      l_i[i][r] = 0.f;
      o_acc[i][r] = (floatx4){0.f, 0.f, 0.f, 0.f};
    }

  int nkv = 2 * t + 2;
  for (int kt = 0; kt < nkv; kt++) {
    int bk = kt * BKV;
    __syncthreads();
#pragma unroll
    for (int r = 0; r < 2; r++) {
      int ch = r * 256 + tid;
      int c = ch >> 8, srow = (ch >> 2) & 63, o8 = ch & 3;
      __builtin_amdgcn_global_load_lds(
          (const __attribute__((address_space(1))) unsigned*)(
              kT + ((size_t)kvh * SS + bk + srow) * 64 + c * 32 + o8 * 8),
          (__attribute__((address_space(3))) unsigned*)(Ks + ch * 8), 16, 0, 0);
      __builtin_amdgcn_global_load_lds(
          (const __attribute__((address_space(1))) unsigned*)(
              vT2 + ((size_t)kvh * 64 + srow) * SS + bk + c * 32 + o8 * 8),
          (__attribute__((address_space(3))) unsigned*)(Vs + ch * 8), 16, 0, 0);
    }
    __syncthreads();

    floatx4 s_acc[2][4];
#pragma unroll
    for (int i = 0; i < 2; i++)
#pragma unroll
      for (int j = 0; j < 4; j++) s_acc[i][j] = (floatx4){0.f, 0.f, 0.f, 0.f};
#pragma unroll
    for (int c = 0; c < 2; c++) {
#pragma unroll
      for (int jk = 0; jk < 4; jk++) {
        short8 kf = *(const short8*)(Ks + c * 2048 + (jk * 16 + ml) * 32 + quad * 8);
#pragma unroll
        for (int i = 0; i < 2; i++)
          s_acc[i][jk] = __builtin_amdgcn_mfma_f32_16x16x32_bf16(qf[i][c], kf, s_acc[i][jk], 0, 0, 0);
      }
    }
    if (bk + BKV - 1 > bq) {
#pragma unroll
      for (int i = 0; i < 2; i++)
#pragma unroll
        for (int jk = 0; jk < 4; jk++)
#pragma unroll
          for (int r = 0; r < 4; r++) {
            int row = bq + wave * 32 + i * 16 + quad * 4 + r;
            int col = bk + jk * 16 + ml;
            if (col > row) s_acc[i][jk][r] = -1e30f;
          }
    }
#pragma unroll
    for (int i = 0; i < 2; i++) {
#pragma unroll
      for (int r = 0; r < 4; r++) {
        float mx = -1e30f;
#pragma unroll
        for (int jk = 0; jk < 4; jk++) mx = fmaxf(mx, s_acc[i][jk][r]);
        for (int o = 1; o < 16; o <<= 1) mx = fmaxf(mx, __shfl_xor(mx, o));
        float mnew = fmaxf(m_i[i][r], mx);
        float alpha = __expf(m_i[i][r] - mnew);
        m_i[i][r] = mnew;
        float rs = 0.f;
#pragma unroll
        for (int jk = 0; jk < 4; jk++) {
          float p = __expf(s_acc[i][jk][r] - mnew);
          s_acc[i][jk][r] = p;
          rs += p;
        }
        for (int o = 1; o < 16; o <<= 1) rs += __shfl_xor(rs, o);
        l_i[i][r] = l_i[i][r] * alpha + rs;
#pragma unroll
        for (int jd = 0; jd < 4; jd++) o_acc[i][jd][r] *= alpha;
      }
    }
#pragma unroll
    for (int i = 0; i < 2; i++)
#pragma unroll
      for (int jk = 0; jk < 4; jk++)
#pragma unroll
        for (int r = 0; r < 4; r++) {
          int row = wave * 32 + i * 16 + quad * 4 + r;
          int col = jk * 16 + ml;
          Ps[(col >> 5) * (128 * 36) + row * 36 + (col & 31)] = f2bf(s_acc[i][jk][r]);
        }
#pragma unroll
    for (int kc = 0; kc < 2; kc++) {
      short8 pf[2];
#pragma unroll
      for (int i = 0; i < 2; i++)
        pf[i] = *(const short8*)(Ps + kc * (128 * 36) + (wave * 32 + i * 16 + ml) * 36 + quad * 8);
#pragma unroll
      for (int jd = 0; jd < 4; jd++) {
        short8 vf = *(const short8*)(Vs + kc * 2048 + (jd * 16 + ml) * 32 + quad * 8);
#pragma unroll
        for (int i = 0; i < 2; i++)
          o_acc[i][jd] = __builtin_amdgcn_mfma_f32_16x16x32_bf16(pf[i], vf, o_acc[i][jd], 0, 0, 0);
      }
    }
  }
#pragma unroll
  for (int i = 0; i < 2; i++) {
    float inv[4];
#pragma unroll
    for (int r = 0; r < 4; r++) inv[r] = 1.f / l_i[i][r];
#pragma unroll
    for (int jd = 0; jd < 4; jd++)
#pragma unroll
      for (int r = 0; r < 4; r++) {
        int row = bq + wave * 32 + i * 16 + quad * 4 + r;
        int col = h * 64 + jd * 16 + ml;
        y[(size_t)row * DD + col] = f2bf(o_acc[i][jd][r] * inv[r]);
      }
  }
}

// ---------------- Gate ----------------
__global__ __launch_bounds__(64) void gate_kernel(const float* __restrict__ hf,
                                                  const float* __restrict__ gw,
                                                  int* __restrict__ ei, float* __restrict__ ew,
                                                  int* __restrict__ cnt) {
  int t = blockIdx.x;
  int lane = threadIdx.x;
  const float* xr = hf + (size_t)t * DD;
  float acc[NE] = {};
  for (int c = 0; c < DD / 64; c++) {
    float xv = xr[lane + 64 * c];
#pragma unroll
    for (int e = 0; e < NE; e++) acc[e] += xv * gw[e * DD + lane + 64 * c];
  }
#pragma unroll
  for (int e = 0; e < NE; e++)
    for (int o = 32; o > 0; o >>= 1) acc[e] += __shfl_xor(acc[e], o);
  if (lane == 0) {
    float mx = acc[0];
    for (int e = 1; e < NE; e++) mx = fmaxf(mx, acc[e]);
    float p[NE], sum = 0.f;
    for (int e = 0; e < NE; e++) { p[e] = __expf(acc[e] - mx); sum += p[e]; }
    for (int e = 0; e < NE; e++) p[e] /= sum;
    int i0 = 0;
    for (int e = 1; e < NE; e++) if (p[e] > p[i0]) i0 = e;
    int i1 = (i0 == 0) ? 1 : 0;
    for (int e = 0; e < NE; e++) if (e != i0 && p[e] > p[i1]) i1 = e;
    float w0 = p[i0], w1 = p[i1], s = w0 + w1;
    ei[t * 2] = i0; ei[t * 2 + 1] = i1;
    ew[t * 2] = w0 / s; ew[t * 2 + 1] = w1 / s;
    atomicAdd(&cnt[i0], 1);
    atomicAdd(&cnt[i1], 1);
  }
}

__global__ void zero_cnt_kernel(int* cnt) {
  if (threadIdx.x < NE) cnt[threadIdx.x] = 0;
}

__global__ void prefix_kernel(const int* __restrict__ cnt, int* __restrict__ poff,
                              int* __restrict__ fill) {
  if (threadIdx.x == 0) {
    int pacc = 0;
    for (int e = 0; e < NE; e++) {
      poff[e] = pacc;
      pacc += (cnt[e] + 127) & ~127;
    }
    poff[NE] = pacc;
  }
  if (threadIdx.x < NE) fill[threadIdx.x] = 0;
}

// tmap[0] = ntiles, tmap[1+i] = (rowoff128 << 3) | expert
__global__ void tilemap_kernel(const int* __restrict__ poff, int* __restrict__ tmap) {
  if (threadIdx.x == 0) {
    int n = 0;
    for (int e = 0; e < NE; e++) {
      int r0 = poff[e] >> 7, r1 = poff[e + 1] >> 7;
      for (int r = r0; r < r1; r++) tmap[1 + n++] = (r << 3) | e;
    }
    tmap[0] = n;
  }
}

__global__ void fill_kernel(const int* __restrict__ ei, const int* __restrict__ poff,
                            int* __restrict__ fill, int* __restrict__ slot_of) {
  int t = blockIdx.x * blockDim.x + threadIdx.x;
  if (t >= SS) return;
  for (int a = 0; a < 2; a++) {
    int e = ei[t * 2 + a];
    int pos = atomicAdd(&fill[e], 1);
    slot_of[t * 2 + a] = poff[e] + pos;
  }
}

__global__ void gather_kernel(const u16* __restrict__ hf16, const int* __restrict__ slot_of,
                              u16* __restrict__ xslot) {
  int t = blockIdx.x;
  uint2 v = ((const uint2*)(hf16 + (size_t)t * DD))[threadIdx.x];
  for (int a = 0; a < 2; a++) {
    int slot = slot_of[t * 2 + a];
    ((uint2*)(xslot + (size_t)slot * DD))[threadIdx.x] = v;
  }
}

// out = h + w0*(p0[s0]+p1[s0]) + w1*(p0[s1]+p1[s1])
__global__ void final_kernel(const float* __restrict__ h, const float* __restrict__ p0,
                             const float* __restrict__ p1, const int* __restrict__ slot_of,
                             const float* __restrict__ ew, float* __restrict__ out) {
  int t = blockIdx.x;
  int s0 = slot_of[t * 2], s1 = slot_of[t * 2 + 1];
  float w0 = ew[t * 2], w1 = ew[t * 2 + 1];
  float4 hv = ((const float4*)(h + (size_t)t * DD))[threadIdx.x];
  float4 a0 = ((const float4*)(p0 + (size_t)s0 * DD))[threadIdx.x];
  float4 a1 = ((const float4*)(p1 + (size_t)s0 * DD))[threadIdx.x];
  float4 b0 = ((const float4*)(p0 + (size_t)s1 * DD))[threadIdx.x];
  float4 b1 = ((const float4*)(p1 + (size_t)s1 * DD))[threadIdx.x];
  float4 o;
  o.x = hv.x + w0 * (a0.x + a1.x) + w1 * (b0.x + b1.x);
  o.y = hv.y + w0 * (a0.y + a1.y) + w1 * (b0.y + b1.y);
  o.z = hv.z + w0 * (a0.z + a1.z) + w1 * (b0.z + b1.z);
  o.w = hv.w + w0 * (a0.w + a1.w) + w1 * (b0.w + b1.w);
  ((float4*)(out + (size_t)t * DD))[threadIdx.x] = o;
}

extern "C" void kernel_launch(void* const* d_in, const int* in_sizes, int n_in,
                              void* d_out, int out_size, void* d_ws, size_t ws_size,
                              hipStream_t stream) {
  const float* x = (const float*)d_in[0];
  const float* wqkv = (const float*)d_in[1];
  const float* wo = (const float*)d_in[2];
  const float* gate_w = (const float*)d_in[3];
  const float* w1 = (const float*)d_in[4];
  const float* w2 = (const float*)d_in[5];
  const float* w3 = (const float*)d_in[6];
  const float* attn_norm_w = (const float*)d_in[7];
  const float* ffn_norm_w = (const float*)d_in[8];
  const float* freqs = (const float*)d_in[9];
  float* out = (float*)d_out;

  char* ws = (char*)d_ws;
  size_t off = 0;
  auto alloc = [&](size_t bytes) -> char* {
    char* p = ws + off;
    off = (off + bytes + 255) & ~(size_t)255;
    return p;
  };
  u16* hn16    = (u16*)alloc((size_t)SS * DD * 2);   // aliased as qT after qkv GEMM
  float* qkv   = (float*)alloc((size_t)SS * QKVN * 4);
  u16* y16     = (u16*)alloc((size_t)SS * DD * 2);
  float* hbuf  = (float*)alloc((size_t)SS * DD * 4);
  float* hf    = (float*)alloc((size_t)SS * DD * 4);
  u16* hf16    = (u16*)alloc((size_t)SS * DD * 2);
  u16* kT      = (u16*)alloc((size_t)NKVH * SS * HDIM * 2);
  u16* vT2     = (u16*)alloc((size_t)NKVH * HDIM * SS * 2);
  u16* wqkv16  = (u16*)alloc((size_t)QKVN * DD * 2);
  u16* wo16    = (u16*)alloc((size_t)DD * DD * 2);
  u16* xslot   = (u16*)alloc((size_t)PCAP * DD * 2);
  u16* x13     = (u16*)alloc((size_t)PCAP * NI * 2);
  float* pbuf  = (float*)alloc((size_t)2 * PCAP * DD * 4);
  int* ei      = (int*)alloc((size_t)SS * 2 * 4);
  float* ew    = (float*)alloc((size_t)SS * 2 * 4);
  int* slot_of = (int*)alloc((size_t)SS * 2 * 4);
  int* cnt     = (int*)alloc(NE * 4);
  int* poff    = (int*)alloc((NE + 1) * 4);
  int* fill    = (int*)alloc(NE * 4);
  int* tmap    = (int*)alloc((NTILEMAX + 1) * 4);
  u16* qT      = hn16;

  auto conv = [&](const float* src, u16* dst, size_t n) {
    int n4 = (int)(n / 4);
    f32_to_bf16_kernel<<<(n4 + 255) / 256, 256, 0, stream>>>(src, dst, n4);
  };

  zero_cnt_kernel<<<1, 64, 0, stream>>>(cnt);
  conv(wqkv, wqkv16, (size_t)QKVN * DD);
  conv(wo, wo16, (size_t)DD * DD);
  // w1/w3/w2: consumed directly as fp32 by moe_stage1/2 (no bulk convert)

  // ---- attention path ----
  rmsnorm_kernel<<<SS, 256, 0, stream>>>(x, attn_norm_w, nullptr, hn16);
  gemm128<<<dim3(SS / 128, QKVN / 128), 256, 0, stream>>>(hn16, wqkv16, qkv, nullptr, QKVN, DD);
  rope_kernel<<<SS, 256, 0, stream>>>(qkv, freqs, qT, kT);
  vtrans_kernel<<<dim3(SS / 64, 4), 256, 0, stream>>>(qkv, vT2);
  attn_flash<<<dim3(SS / BQ, NH), 256, 0, stream>>>(qT, kT, vT2, y16);
  gemm128<<<dim3(SS / 128, DD / 128), 256, 0, stream>>>(y16, wo16, hbuf, x, DD, DD);

  // ---- MoE path ----
  rmsnorm_kernel<<<SS, 256, 0, stream>>>(hbuf, ffn_norm_w, hf, hf16);
  gate_kernel<<<SS, 64, 0, stream>>>(hf, gate_w, ei, ew, cnt);
  prefix_kernel<<<1, 64, 0, stream>>>(cnt, poff, fill);
  tilemap_kernel<<<1, 64, 0, stream>>>(poff, tmap);
  fill_kernel<<<(SS + 255) / 256, 256, 0, stream>>>(ei, poff, fill, slot_of);
  gather_kernel<<<SS, 256, 0, stream>>>(hf16, slot_of, xslot);
  // XCD-affinity grids: stage1 (8, 7*40), stage2 (8, 4*40)
  moe_stage1<<<dim3(8, (NI / 64 / 8) * NTILEMAX), 256, 0, stream>>>(xslot, w1, w3, tmap, x13);
  moe_stage2<<<dim3(8, 4 * NTILEMAX), 256, 0, stream>>>(x13, w2, tmap, pbuf);
  final_kernel<<<SS, 256, 0, stream>>>(hbuf, pbuf, pbuf + (size_t)PCAP * DD, slot_of, ew, out);
}